// Round 14
// baseline (789.199 us; speedup 1.0000x reference)
//
#include <hip/hip_runtime.h>
#include <hip/hip_bf16.h>
#include <hip/hip_fp16.h>
#include <math.h>

constexpr int NE = 400000;
constexpr int NN = 40000;
constexpr int CD = 64;
constexpr int NGRAPH = 64;
constexpr int SCAN_BLOCKS = (NN + 255) / 256;   // 157

// ---------------- fc1: x0 = relu(x @ fc1_w + b) ----------------
__global__ void k_fc1(const float* __restrict__ x,
                      const float* __restrict__ w,
                      const float* __restrict__ b,
                      float* __restrict__ out) {
    int i = blockIdx.x * 256 + threadIdx.x;
    if (i >= NN * CD) return;
    int n = i >> 6, c = i & 63;
    float acc = b[c];
    #pragma unroll
    for (int k = 0; k < 9; ++k)
        acc = fmaf(x[n * 9 + k], w[k * 64 + c], acc);
    out[i] = fmaxf(acc, 0.f);
}

// ---------------- edge counts ----------------
__global__ void k_count(const int* __restrict__ ei, int* __restrict__ cnt) {
    int e = blockIdx.x * 256 + threadIdx.x;
    if (e >= NE) return;
    atomicAdd(&cnt[ei[e]], 1);
}

// ---------------- parallel scan, phase 1: per-block partial sums ----------------
__global__ void k_scan_part(const int* __restrict__ cnt, int* __restrict__ partials) {
    __shared__ int red[256];
    const int tid = threadIdx.x;
    const int i = blockIdx.x * 256 + tid;
    red[tid] = (i < NN) ? cnt[i] : 0;
    __syncthreads();
    for (int s = 128; s > 0; s >>= 1) {
        if (tid < s) red[tid] += red[tid + s];
        __syncthreads();
    }
    if (tid == 0) partials[blockIdx.x] = red[0];
}

// ---------------- phase 2: single-block scan of partials (nblk <= 256) ----------------
__global__ void k_scan_mid(const int* __restrict__ partials, int* __restrict__ offs, int nblk) {
    __shared__ int part[256];
    const int tid = threadIdx.x;
    const int v = (tid < nblk) ? partials[tid] : 0;
    part[tid] = v;
    __syncthreads();
    for (int off = 1; off < 256; off <<= 1) {
        int t = (tid >= off) ? part[tid - off] : 0;
        __syncthreads();
        part[tid] += t;
        __syncthreads();
    }
    if (tid < nblk) offs[tid] = part[tid] - v;   // exclusive
}

// ---------------- phase 3: in-block exclusive scan + base -> row_start, cursor ----------------
__global__ void k_scan_fill(const int* __restrict__ cnt, const int* __restrict__ offs,
                            int* __restrict__ row_start, int* __restrict__ cursor) {
    __shared__ int part[256];
    const int tid = threadIdx.x;
    const int i = blockIdx.x * 256 + tid;
    const int v = (i < NN) ? cnt[i] : 0;
    part[tid] = v;
    __syncthreads();
    for (int off = 1; off < 256; off <<= 1) {
        int t = (tid >= off) ? part[tid - off] : 0;
        __syncthreads();
        part[tid] += t;
        __syncthreads();
    }
    const int excl = part[tid] - v + offs[blockIdx.x];
    if (i < NN) { row_start[i] = excl; cursor[i] = excl; }
    if (i == NN - 1) row_start[NN] = NE;
}

// ---------------- scatter edge ids into CSR order ----------------
__global__ void k_scatter(const int* __restrict__ ei, int* __restrict__ cursor,
                          int* __restrict__ perm) {
    int e = blockIdx.x * 256 + threadIdx.x;
    if (e >= NE) return;
    int pos = atomicAdd(&cursor[ei[e]], 1);
    perm[pos] = e;
}

// ---------------- pre-gather packed edge data into CSR order ----------------
__global__ void k_edge_gather(const int* __restrict__ ei, const float* __restrict__ ew,
                              const int* __restrict__ perm,
                              int2* __restrict__ rcP, float4* __restrict__ ewP) {
    int p = blockIdx.x * 256 + threadIdx.x;
    if (p >= NE) return;
    const int e = perm[p];
    rcP[p] = make_int2(ei[e], ei[NE + e]);
    ewP[p] = make_float4(ew[3 * e], ew[3 * e + 1], ew[3 * e + 2], 0.f);
}

// ---------------- node projection, split output:
// Pi[n][0:64]  = bf + x@Wf_top, Pi[n][64:128] = bs + x@Ws_top  (row-side, f32)
// Pj16[n][c] = half2(x@Wf_bot[c], x@Ws_bot[c])                 (col-side, gathered)
__global__ void k_proj(const float* __restrict__ x,
                       const float* __restrict__ wf, const float* __restrict__ bfp,
                       const float* __restrict__ wsp, const float* __restrict__ bsp,
                       float* __restrict__ Pi, __half2* __restrict__ Pj16) {
    __shared__ __align__(16) float xs[8][64];
    __shared__ float sS[8][64];
    const int tid = threadIdx.x;
    const int n0 = blockIdx.x * 8;
    for (int i = tid; i < 512; i += 256)
        xs[i >> 6][i & 63] = x[(size_t)(n0 + (i >> 6)) * 64 + (i & 63)];
    __syncthreads();
    const int q = tid >> 6, c = tid & 63;
    const float* __restrict__ wp = ((q & 2) ? wsp : wf) + ((q & 1) ? 64 * 64 : 0) + c;
    const float bias = (q == 0) ? bfp[c] : (q == 2 ? bsp[c] : 0.f);
    float acc[8];
    #pragma unroll
    for (int g = 0; g < 8; ++g) acc[g] = bias;
    for (int k4 = 0; k4 < 64; k4 += 4) {
        const float w0 = wp[(k4 + 0) * 64];
        const float w1 = wp[(k4 + 1) * 64];
        const float w2 = wp[(k4 + 2) * 64];
        const float w3 = wp[(k4 + 3) * 64];
        #pragma unroll
        for (int g = 0; g < 8; ++g) {
            const float4 xv = *(const float4*)&xs[g][k4];
            acc[g] = fmaf(xv.x, w0, acc[g]);
            acc[g] = fmaf(xv.y, w1, acc[g]);
            acc[g] = fmaf(xv.z, w2, acc[g]);
            acc[g] = fmaf(xv.w, w3, acc[g]);
        }
    }
    if (q == 3) {
        #pragma unroll
        for (int g = 0; g < 8; ++g) sS[g][c] = acc[g];
    }
    __syncthreads();
    #pragma unroll
    for (int g = 0; g < 8; ++g) {
        const size_t n = n0 + g;
        if (q == 0)      Pi[n * 128 + c]      = acc[g];
        else if (q == 2) Pi[n * 128 + 64 + c] = acc[g];
        else if (q == 1) Pj16[n * 64 + c]     = __floats2half2_rn(acc[g], sS[g][c]);
    }
}

// ---------------- edge-parallel row-range conv: 8 rows/block, chunked waves,
//                  register accumulation with flush-on-row-change ----------------
__launch_bounds__(256, 8)
__global__ void k_edge_range(const __half2* __restrict__ Pj,
                             const float* __restrict__ Pi,
                             const int2* __restrict__ rcP, const float4* __restrict__ ewP,
                             const float* __restrict__ wfe, const float* __restrict__ wse,
                             const int* __restrict__ rs,
                             const float* __restrict__ xin, float* __restrict__ out) {
    __shared__ float piS[8][128];         // staged row-side projections (4 KB)
    __shared__ float accS[4][8][64];      // per-wave accumulators (8 KB)
    __shared__ int rsS[9];
    const int tid = threadIdx.x;
    const int c = tid & 63, wv = tid >> 6;
    const int r0 = blockIdx.x * 8;
    for (int i = tid; i < 1024; i += 256)
        piS[i >> 7][i & 127] = Pi[(size_t)r0 * 128 + i];
    for (int i = tid; i < 2048; i += 256)
        ((float*)accS)[i] = 0.f;
    if (tid < 9) rsS[tid] = rs[r0 + tid];
    __syncthreads();
    const float wf0 = wfe[c], wf1 = wfe[64 + c], wf2 = wfe[128 + c];
    const float ws0 = wse[c], ws1 = wse[64 + c], ws2 = wse[128 + c];
    const int pbeg = rsS[0], pend = rsS[8];
    // contiguous chunk per wave (row locality for register accumulation)
    const int total = pend - pbeg;
    const int per = (total + 3) >> 2;
    const int mybeg = pbeg + wv * per;
    const int myend = min(mybeg + per, pend);
    int crow = -1;
    float racc = 0.f, pfc = 0.f, psc = 0.f;
    for (int p = mybeg; p < myend; ++p) {
        const int2 rc = rcP[p];
        const float4 e = ewP[p];
        const float2 J = __half22float2(Pj[(size_t)rc.y * 64 + c]);
        const int row = rc.x - r0;      // wave-uniform
        if (row != crow) {              // uniform branch
            if (crow >= 0) accS[wv][crow][c] = racc;
            crow = row; racc = 0.f;
            pfc = piS[row][c];
            psc = piS[row][64 + c];
        }
        const float af = pfc + J.x + e.x * wf0 + e.y * wf1 + e.z * wf2;
        const float as = psc + J.y + e.x * ws0 + e.y * ws1 + e.z * ws2;
        const float sg = 1.f / (1.f + __expf(-af));
        const float sp = (as > 20.f) ? as : __logf(1.f + __expf(as));
        racc = fmaf(sg, sp, racc);
    }
    if (crow >= 0) accS[wv][crow][c] = racc;
    __syncthreads();
    for (int i = tid; i < 512; i += 256) {
        const int row = i >> 6, ch = i & 63;
        const float s = accS[0][row][ch] + accS[1][row][ch]
                      + accS[2][row][ch] + accS[3][row][ch];
        const int deg = rsS[row + 1] - rsS[row];
        const size_t o = (size_t)(r0 + row) * 64 + ch;
        out[o] = fmaxf(fmaf(s, 1.f / (float)max(deg, 1), xin[o]), 0.f);
    }
}

// ---------------- fused GRU: h = GRU(m, h), weights from L2 ----------------
__global__ void k_gru_fused(const float* __restrict__ m, float* __restrict__ h,
                            const float* __restrict__ wih, const float* __restrict__ bih,
                            const float* __restrict__ whh, const float* __restrict__ bhh) {
    __shared__ __align__(16) float ms[32][64];
    __shared__ __align__(16) float hs[32][64];
    const int tid = threadIdx.x;
    const int n0 = blockIdx.x * 32;
    for (int i = tid; i < 2048; i += 256) {
        ms[i >> 6][i & 63] = m[(size_t)n0 * 64 + i];
        hs[i >> 6][i & 63] = h[(size_t)n0 * 64 + i];
    }
    __syncthreads();
    const int c = tid & 63, tg = tid >> 6;
    float ir[8], iz[8], inn[8], hr[8], hz[8], hn[8];
    #pragma unroll
    for (int j = 0; j < 8; ++j) { ir[j]=0.f; iz[j]=0.f; inn[j]=0.f; hr[j]=0.f; hz[j]=0.f; hn[j]=0.f; }
    for (int k4 = 0; k4 < 64; k4 += 4) {
        float wir[4], wiz[4], win[4], whr[4], whz[4], whn[4];
        #pragma unroll
        for (int u = 0; u < 4; ++u) {
            const int k = k4 + u;
            wir[u] = wih[k * 192 + c];
            wiz[u] = wih[k * 192 + 64 + c];
            win[u] = wih[k * 192 + 128 + c];
            whr[u] = whh[k * 192 + c];
            whz[u] = whh[k * 192 + 64 + c];
            whn[u] = whh[k * 192 + 128 + c];
        }
        #pragma unroll
        for (int j = 0; j < 8; ++j) {
            const int nrow = j * 4 + tg;
            const float4 mv = *(const float4*)&ms[nrow][k4];
            const float4 hv = *(const float4*)&hs[nrow][k4];
            ir[j]  = fmaf(mv.x, wir[0], ir[j]);  ir[j]  = fmaf(mv.y, wir[1], ir[j]);
            ir[j]  = fmaf(mv.z, wir[2], ir[j]);  ir[j]  = fmaf(mv.w, wir[3], ir[j]);
            iz[j]  = fmaf(mv.x, wiz[0], iz[j]);  iz[j]  = fmaf(mv.y, wiz[1], iz[j]);
            iz[j]  = fmaf(mv.z, wiz[2], iz[j]);  iz[j]  = fmaf(mv.w, wiz[3], iz[j]);
            inn[j] = fmaf(mv.x, win[0], inn[j]); inn[j] = fmaf(mv.y, win[1], inn[j]);
            inn[j] = fmaf(mv.z, win[2], inn[j]); inn[j] = fmaf(mv.w, win[3], inn[j]);
            hr[j]  = fmaf(hv.x, whr[0], hr[j]);  hr[j]  = fmaf(hv.y, whr[1], hr[j]);
            hr[j]  = fmaf(hv.z, whr[2], hr[j]);  hr[j]  = fmaf(hv.w, whr[3], hr[j]);
            hz[j]  = fmaf(hv.x, whz[0], hz[j]);  hz[j]  = fmaf(hv.y, whz[1], hz[j]);
            hz[j]  = fmaf(hv.z, whz[2], hz[j]);  hz[j]  = fmaf(hv.w, whz[3], hz[j]);
            hn[j]  = fmaf(hv.x, whn[0], hn[j]);  hn[j]  = fmaf(hv.y, whn[1], hn[j]);
            hn[j]  = fmaf(hv.z, whn[2], hn[j]);  hn[j]  = fmaf(hv.w, whn[3], hn[j]);
        }
    }
    const float bir = bih[c], biz = bih[64 + c], bin = bih[128 + c];
    const float bhr = bhh[c], bhz = bhh[64 + c], bhn = bhh[128 + c];
    #pragma unroll
    for (int j = 0; j < 8; ++j) {
        const int n = n0 + j * 4 + tg;
        const float r  = 1.f / (1.f + __expf(-((ir[j] + bir) + (hr[j] + bhr))));
        const float zg = 1.f / (1.f + __expf(-((iz[j] + biz) + (hz[j] + bhz))));
        const float ng = tanhf((inn[j] + bin) + r * (hn[j] + bhn));
        h[(size_t)n * 64 + c] = (1.f - zg) * ng + zg * hs[j * 4 + tg][c];
    }
}

// ---------------- first-node-per-graph indices (searchsorted) ----------------
__global__ void k_idx(const int* __restrict__ batch, int* __restrict__ idx) {
    int g = threadIdx.x;
    if (g >= NGRAPH) return;
    int lo = 0, hi = NN;
    while (lo < hi) {
        int mid = (lo + hi) >> 1;
        if (batch[mid] < g) lo = mid + 1; else hi = mid;
    }
    idx[g] = lo;
}

// ---------------- readout head: all weights/activations in LDS ----------------
__global__ void k_head(const float* __restrict__ h, const int* __restrict__ idx,
                       const float* __restrict__ fcsw, const float* __restrict__ fcsb,
                       const float* __restrict__ f2cw, const float* __restrict__ f2cb,
                       const float* __restrict__ f3cw, const float* __restrict__ f3cb,
                       const float* __restrict__ f2dw, const float* __restrict__ f2db,
                       const float* __restrict__ f3dw, const float* __restrict__ f3db,
                       float* __restrict__ out) {
    __shared__ float hsB[4096];  // hsel -> xgs
    __shared__ float waB[4096];  // fcsw -> xcs
    __shared__ float wbB[4096];  // f2cw -> xds
    __shared__ float wcB[4096];  // f2dw -> f3 weights
    const int tid = threadIdx.x;
    for (int i = tid; i < 4096; i += 256) {
        int g = i >> 6, k = i & 63;
        hsB[i] = h[(size_t)idx[g] * 64 + k];
        waB[i] = fcsw[i];
        wbB[i] = f2cw[i];
        wcB[i] = f2dw[i];
    }
    __syncthreads();
    float v[16];
    #pragma unroll
    for (int j = 0; j < 16; ++j) {
        const int i = j * 256 + tid, g = i >> 6, c = i & 63;
        float a = fcsb[c];
        for (int k = 0; k < 64; ++k) a = fmaf(hsB[g * 64 + k], waB[k * 64 + c], a);
        v[j] = fmaxf(a, 0.f);
    }
    __syncthreads();
    #pragma unroll
    for (int j = 0; j < 16; ++j) hsB[j * 256 + tid] = v[j];   // xgs
    __syncthreads();
    float vc[16], vd[16];
    #pragma unroll
    for (int j = 0; j < 16; ++j) {
        const int i = j * 256 + tid, g = i >> 6, c = i & 63;
        float a1 = f2cb[c], a2 = f2db[c];
        for (int k = 0; k < 64; ++k) {
            const float xv = hsB[g * 64 + k];
            a1 = fmaf(xv, wbB[k * 64 + c], a1);
            a2 = fmaf(xv, wcB[k * 64 + c], a2);
        }
        vc[j] = fmaxf(a1, 0.f);
        vd[j] = fmaxf(a2, 0.f);
    }
    __syncthreads();
    #pragma unroll
    for (int j = 0; j < 16; ++j) {
        waB[j * 256 + tid] = vc[j];   // xcs
        wbB[j * 256 + tid] = vd[j];   // xds
    }
    if (tid < 128) wcB[tid] = f3cw[tid];
    else           wcB[tid] = f3dw[tid - 128];
    __syncthreads();
    if (tid < 128) {
        int g = tid >> 1, j = tid & 1;
        float a = f3cb[j];
        for (int k = 0; k < 64; ++k) a = fmaf(waB[g * 64 + k], wcB[k * 2 + j], a);
        out[g * 2 + j] = 1.f / (1.f + expf(-a));
    } else {
        int t = tid - 128, g = t >> 1, j = t & 1;
        float a = f3db[j];
        for (int k = 0; k < 64; ++k) a = fmaf(wbB[g * 64 + k], wcB[128 + k * 2 + j], a);
        out[128 + g * 2 + j] = a;
    }
}

// ---------------- host launcher ----------------
extern "C" void kernel_launch(void* const* d_in, const int* in_sizes, int n_in,
                              void* d_out, int out_size, void* d_ws, size_t ws_size,
                              hipStream_t stream) {
    (void)in_sizes; (void)n_in; (void)out_size; (void)ws_size;
    const float* x    = (const float*)d_in[0];
    const int* ei1    = (const int*)d_in[1];
    const int* ei2    = (const int*)d_in[2];
    const float* w1   = (const float*)d_in[3];
    const float* w2   = (const float*)d_in[4];
    const int* batch  = (const int*)d_in[5];
    const float* fc1w = (const float*)d_in[6];
    const float* fc1b = (const float*)d_in[7];
    const float* lfw  = (const float*)d_in[8];
    const float* lfb  = (const float*)d_in[9];
    const float* lsw  = (const float*)d_in[10];
    const float* lsb  = (const float*)d_in[11];
    const float* wih  = (const float*)d_in[12];
    const float* bih  = (const float*)d_in[13];
    const float* whh  = (const float*)d_in[14];
    const float* bhh  = (const float*)d_in[15];
    const float* fcsw = (const float*)d_in[16];
    const float* fcsb = (const float*)d_in[17];
    const float* f2cw = (const float*)d_in[18];
    const float* f2cb = (const float*)d_in[19];
    const float* f3cw = (const float*)d_in[20];
    const float* f3cb = (const float*)d_in[21];
    const float* f2dw = (const float*)d_in[22];
    const float* f2db = (const float*)d_in[23];
    const float* f3dw = (const float*)d_in[24];
    const float* f3db = (const float*)d_in[25];

    char* ws = (char*)d_ws;
    size_t off = 0;
    auto alloc = [&](size_t bytes) { char* p = ws + off; off += (bytes + 255) & ~size_t(255); return p; };
    float*   Pi    = (float*)alloc(size_t(NN) * 128 * 4);      // 20.5 MB
    __half2* Pj16  = (__half2*)alloc(size_t(NN) * 64 * 4);     // 10.2 MB
    float*   hbuf  = (float*)alloc(size_t(NN) * CD * 4);
    float*   mbuf  = (float*)alloc(size_t(NN) * CD * 4);
    int*   cnt1  = (int*)alloc(size_t(NN) * 4);
    int*   cnt2  = (int*)alloc(size_t(NN) * 4);
    int*   rs1   = (int*)alloc(size_t(NN + 1) * 4);
    int*   rs2   = (int*)alloc(size_t(NN + 1) * 4);
    int*   cur1  = (int*)alloc(size_t(NN + 1) * 4);
    int*   cur2  = (int*)alloc(size_t(NN + 1) * 4);
    int*   perm1 = (int*)alloc(size_t(NE) * 4);
    int*   perm2 = (int*)alloc(size_t(NE) * 4);
    int2*  rcP1  = (int2*)alloc(size_t(NE) * 8);
    int2*  rcP2  = (int2*)alloc(size_t(NE) * 8);
    float4* ewP1 = (float4*)alloc(size_t(NE) * 16);
    float4* ewP2 = (float4*)alloc(size_t(NE) * 16);
    int*   part1 = (int*)alloc(256 * 4);
    int*   part2 = (int*)alloc(256 * 4);
    int*   offs1 = (int*)alloc(256 * 4);
    int*   offs2 = (int*)alloc(256 * 4);
    int*   idx   = (int*)alloc(256);

    const int NB_NC = (NN * CD + 255) / 256;
    const int NB_E  = (NE + 255) / 256;
    const int EDGE_BLOCKS = NN / 8;    // 5000 row-range blocks
    const int PROJ_BLOCKS = NN / 8;    // 5000
    const int GRU_BLOCKS  = NN / 32;   // 1250

    const float* lfe = lfw + 128 * 64;
    const float* lse = lsw + 128 * 64;

    // CSR build (parallel scan) + packed edge pre-gather
    hipMemsetAsync(cnt1, 0, size_t(NN) * 4, stream);
    hipMemsetAsync(cnt2, 0, size_t(NN) * 4, stream);
    k_count<<<NB_E, 256, 0, stream>>>(ei1, cnt1);
    k_count<<<NB_E, 256, 0, stream>>>(ei2, cnt2);
    k_scan_part<<<SCAN_BLOCKS, 256, 0, stream>>>(cnt1, part1);
    k_scan_part<<<SCAN_BLOCKS, 256, 0, stream>>>(cnt2, part2);
    k_scan_mid<<<1, 256, 0, stream>>>(part1, offs1, SCAN_BLOCKS);
    k_scan_mid<<<1, 256, 0, stream>>>(part2, offs2, SCAN_BLOCKS);
    k_scan_fill<<<SCAN_BLOCKS, 256, 0, stream>>>(cnt1, offs1, rs1, cur1);
    k_scan_fill<<<SCAN_BLOCKS, 256, 0, stream>>>(cnt2, offs2, rs2, cur2);
    k_scatter<<<NB_E, 256, 0, stream>>>(ei1, cur1, perm1);
    k_scatter<<<NB_E, 256, 0, stream>>>(ei2, cur2, perm2);
    k_edge_gather<<<NB_E, 256, 0, stream>>>(ei1, w1, perm1, rcP1, ewP1);
    k_edge_gather<<<NB_E, 256, 0, stream>>>(ei2, w2, perm2, rcP2, ewP2);

    k_fc1<<<NB_NC, 256, 0, stream>>>(x, fc1w, fc1b, hbuf);

    for (int it = 0; it < 3; ++it) {
        k_proj<<<PROJ_BLOCKS, 256, 0, stream>>>(hbuf, lfw, lfb, lsw, lsb, Pi, Pj16);
        k_edge_range<<<EDGE_BLOCKS, 256, 0, stream>>>(Pj16, Pi, rcP2, ewP2,
                                                      lfe, lse, rs2, hbuf, mbuf);
        k_proj<<<PROJ_BLOCKS, 256, 0, stream>>>(mbuf, lfw, lfb, lsw, lsb, Pi, Pj16);
        k_edge_range<<<EDGE_BLOCKS, 256, 0, stream>>>(Pj16, Pi, rcP1, ewP1,
                                                      lfe, lse, rs1, mbuf, mbuf);
        k_gru_fused<<<GRU_BLOCKS, 256, 0, stream>>>(mbuf, hbuf, wih, bih, whh, bhh);
    }

    k_idx<<<1, 64, 0, stream>>>(batch, idx);
    k_head<<<1, 256, 0, stream>>>(hbuf, idx, fcsw, fcsb, f2cw, f2cb, f3cw, f3cb,
                                  f2dw, f2db, f3dw, f3db, (float*)d_out);
}

// Round 15
// 737.608 us; speedup vs baseline: 1.0699x; 1.0699x over previous
//
#include <hip/hip_runtime.h>
#include <hip/hip_bf16.h>
#include <hip/hip_fp16.h>
#include <math.h>

constexpr int NE = 400000;
constexpr int NN = 40000;
constexpr int CD = 64;
constexpr int NGRAPH = 64;
constexpr int SCAN_BLOCKS = (NN + 255) / 256;   // 157

// ---------------- fc1: x0 = relu(x @ fc1_w + b) ----------------
__global__ void k_fc1(const float* __restrict__ x,
                      const float* __restrict__ w,
                      const float* __restrict__ b,
                      float* __restrict__ out) {
    int i = blockIdx.x * 256 + threadIdx.x;
    if (i >= NN * CD) return;
    int n = i >> 6, c = i & 63;
    float acc = b[c];
    #pragma unroll
    for (int k = 0; k < 9; ++k)
        acc = fmaf(x[n * 9 + k], w[k * 64 + c], acc);
    out[i] = fmaxf(acc, 0.f);
}

// ---------------- edge counts ----------------
__global__ void k_count(const int* __restrict__ ei, int* __restrict__ cnt) {
    int e = blockIdx.x * 256 + threadIdx.x;
    if (e >= NE) return;
    atomicAdd(&cnt[ei[e]], 1);
}

// ---------------- parallel scan, phase 1: per-block partial sums ----------------
__global__ void k_scan_part(const int* __restrict__ cnt, int* __restrict__ partials) {
    __shared__ int red[256];
    const int tid = threadIdx.x;
    const int i = blockIdx.x * 256 + tid;
    red[tid] = (i < NN) ? cnt[i] : 0;
    __syncthreads();
    for (int s = 128; s > 0; s >>= 1) {
        if (tid < s) red[tid] += red[tid + s];
        __syncthreads();
    }
    if (tid == 0) partials[blockIdx.x] = red[0];
}

// ---------------- phase 2: single-block scan of partials (nblk <= 256) ----------------
__global__ void k_scan_mid(const int* __restrict__ partials, int* __restrict__ offs, int nblk) {
    __shared__ int part[256];
    const int tid = threadIdx.x;
    const int v = (tid < nblk) ? partials[tid] : 0;
    part[tid] = v;
    __syncthreads();
    for (int off = 1; off < 256; off <<= 1) {
        int t = (tid >= off) ? part[tid - off] : 0;
        __syncthreads();
        part[tid] += t;
        __syncthreads();
    }
    if (tid < nblk) offs[tid] = part[tid] - v;   // exclusive
}

// ---------------- phase 3: in-block exclusive scan + base -> row_start, cursor ----------------
__global__ void k_scan_fill(const int* __restrict__ cnt, const int* __restrict__ offs,
                            int* __restrict__ row_start, int* __restrict__ cursor) {
    __shared__ int part[256];
    const int tid = threadIdx.x;
    const int i = blockIdx.x * 256 + tid;
    const int v = (i < NN) ? cnt[i] : 0;
    part[tid] = v;
    __syncthreads();
    for (int off = 1; off < 256; off <<= 1) {
        int t = (tid >= off) ? part[tid - off] : 0;
        __syncthreads();
        part[tid] += t;
        __syncthreads();
    }
    const int excl = part[tid] - v + offs[blockIdx.x];
    if (i < NN) { row_start[i] = excl; cursor[i] = excl; }
    if (i == NN - 1) row_start[NN] = NE;
}

// ---------------- scatter edge ids into CSR order ----------------
__global__ void k_scatter(const int* __restrict__ ei, int* __restrict__ cursor,
                          int* __restrict__ perm) {
    int e = blockIdx.x * 256 + threadIdx.x;
    if (e >= NE) return;
    int pos = atomicAdd(&cursor[ei[e]], 1);
    perm[pos] = e;
}

// ---------------- pre-gather packed edge data into CSR order ----------------
__global__ void k_edge_gather(const int* __restrict__ ei, const float* __restrict__ ew,
                              const int* __restrict__ perm,
                              int2* __restrict__ rcP, float4* __restrict__ ewP) {
    int p = blockIdx.x * 256 + threadIdx.x;
    if (p >= NE) return;
    const int e = perm[p];
    rcP[p] = make_int2(ei[e], ei[NE + e]);
    ewP[p] = make_float4(ew[3 * e], ew[3 * e + 1], ew[3 * e + 2], 0.f);
}

// ---------------- node projection, split output:
// Pi[n][0:64]  = bf + x@Wf_top, Pi[n][64:128] = bs + x@Ws_top  (row-side, f32)
// Pj16[n][c] = half2(x@Wf_bot[c], x@Ws_bot[c])                 (col-side, gathered)
__global__ void k_proj(const float* __restrict__ x,
                       const float* __restrict__ wf, const float* __restrict__ bfp,
                       const float* __restrict__ wsp, const float* __restrict__ bsp,
                       float* __restrict__ Pi, __half2* __restrict__ Pj16) {
    __shared__ __align__(16) float xs[8][64];
    __shared__ float sS[8][64];
    const int tid = threadIdx.x;
    const int n0 = blockIdx.x * 8;
    for (int i = tid; i < 512; i += 256)
        xs[i >> 6][i & 63] = x[(size_t)(n0 + (i >> 6)) * 64 + (i & 63)];
    __syncthreads();
    const int q = tid >> 6, c = tid & 63;
    const float* __restrict__ wp = ((q & 2) ? wsp : wf) + ((q & 1) ? 64 * 64 : 0) + c;
    const float bias = (q == 0) ? bfp[c] : (q == 2 ? bsp[c] : 0.f);
    float acc[8];
    #pragma unroll
    for (int g = 0; g < 8; ++g) acc[g] = bias;
    for (int k4 = 0; k4 < 64; k4 += 4) {
        const float w0 = wp[(k4 + 0) * 64];
        const float w1 = wp[(k4 + 1) * 64];
        const float w2 = wp[(k4 + 2) * 64];
        const float w3 = wp[(k4 + 3) * 64];
        #pragma unroll
        for (int g = 0; g < 8; ++g) {
            const float4 xv = *(const float4*)&xs[g][k4];
            acc[g] = fmaf(xv.x, w0, acc[g]);
            acc[g] = fmaf(xv.y, w1, acc[g]);
            acc[g] = fmaf(xv.z, w2, acc[g]);
            acc[g] = fmaf(xv.w, w3, acc[g]);
        }
    }
    if (q == 3) {
        #pragma unroll
        for (int g = 0; g < 8; ++g) sS[g][c] = acc[g];
    }
    __syncthreads();
    #pragma unroll
    for (int g = 0; g < 8; ++g) {
        const size_t n = n0 + g;
        if (q == 0)      Pi[n * 128 + c]      = acc[g];
        else if (q == 2) Pi[n * 128 + 64 + c] = acc[g];
        else if (q == 1) Pj16[n * 64 + c]     = __floats2half2_rn(acc[g], sS[g][c]);
    }
}

// ---------------- edge-parallel row-range conv: 8 rows/block, wave=edge,
//                  strided positions + LDS accumulate (round-13 proven form) ----------------
__launch_bounds__(256, 8)
__global__ void k_edge_range(const __half2* __restrict__ Pj,
                             const float* __restrict__ Pi,
                             const int2* __restrict__ rcP, const float4* __restrict__ ewP,
                             const float* __restrict__ wfe, const float* __restrict__ wse,
                             const int* __restrict__ rs,
                             const float* __restrict__ xin, float* __restrict__ out) {
    __shared__ float piS[8][128];         // staged row-side projections (4 KB)
    __shared__ float accS[4][8][64];      // per-wave accumulators (8 KB)
    __shared__ int rsS[9];
    const int tid = threadIdx.x;
    const int c = tid & 63, wv = tid >> 6;
    const int r0 = blockIdx.x * 8;
    for (int i = tid; i < 1024; i += 256)
        piS[i >> 7][i & 127] = Pi[(size_t)r0 * 128 + i];
    for (int i = tid; i < 2048; i += 256)
        ((float*)accS)[i] = 0.f;
    if (tid < 9) rsS[tid] = rs[r0 + tid];
    __syncthreads();
    const float wf0 = wfe[c], wf1 = wfe[64 + c], wf2 = wfe[128 + c];
    const float ws0 = wse[c], ws1 = wse[64 + c], ws2 = wse[128 + c];
    const int pbeg = rsS[0], pend = rsS[8];
    #pragma unroll 4
    for (int p = pbeg + wv; p < pend; p += 4) {
        const int2 rc = rcP[p];
        const float4 e = ewP[p];
        const float2 J = __half22float2(Pj[(size_t)rc.y * 64 + c]);
        const int row = rc.x - r0;
        const float af = piS[row][c]      + J.x + e.x * wf0 + e.y * wf1 + e.z * wf2;
        const float as = piS[row][64 + c] + J.y + e.x * ws0 + e.y * ws1 + e.z * ws2;
        const float sg = 1.f / (1.f + __expf(-af));
        const float sp = (as > 20.f) ? as : __logf(1.f + __expf(as));
        accS[wv][row][c] += sg * sp;
    }
    __syncthreads();
    for (int i = tid; i < 512; i += 256) {
        const int row = i >> 6, ch = i & 63;
        const float s = accS[0][row][ch] + accS[1][row][ch]
                      + accS[2][row][ch] + accS[3][row][ch];
        const int deg = rsS[row + 1] - rsS[row];
        const size_t o = (size_t)(r0 + row) * 64 + ch;
        out[o] = fmaxf(fmaf(s, 1.f / (float)max(deg, 1), xin[o]), 0.f);
    }
}

// ---------------- fused GRU: h = GRU(m, h), weights from L2 ----------------
__global__ void k_gru_fused(const float* __restrict__ m, float* __restrict__ h,
                            const float* __restrict__ wih, const float* __restrict__ bih,
                            const float* __restrict__ whh, const float* __restrict__ bhh) {
    __shared__ __align__(16) float ms[32][64];
    __shared__ __align__(16) float hs[32][64];
    const int tid = threadIdx.x;
    const int n0 = blockIdx.x * 32;
    for (int i = tid; i < 2048; i += 256) {
        ms[i >> 6][i & 63] = m[(size_t)n0 * 64 + i];
        hs[i >> 6][i & 63] = h[(size_t)n0 * 64 + i];
    }
    __syncthreads();
    const int c = tid & 63, tg = tid >> 6;
    float ir[8], iz[8], inn[8], hr[8], hz[8], hn[8];
    #pragma unroll
    for (int j = 0; j < 8; ++j) { ir[j]=0.f; iz[j]=0.f; inn[j]=0.f; hr[j]=0.f; hz[j]=0.f; hn[j]=0.f; }
    for (int k4 = 0; k4 < 64; k4 += 4) {
        float wir[4], wiz[4], win[4], whr[4], whz[4], whn[4];
        #pragma unroll
        for (int u = 0; u < 4; ++u) {
            const int k = k4 + u;
            wir[u] = wih[k * 192 + c];
            wiz[u] = wih[k * 192 + 64 + c];
            win[u] = wih[k * 192 + 128 + c];
            whr[u] = whh[k * 192 + c];
            whz[u] = whh[k * 192 + 64 + c];
            whn[u] = whh[k * 192 + 128 + c];
        }
        #pragma unroll
        for (int j = 0; j < 8; ++j) {
            const int nrow = j * 4 + tg;
            const float4 mv = *(const float4*)&ms[nrow][k4];
            const float4 hv = *(const float4*)&hs[nrow][k4];
            ir[j]  = fmaf(mv.x, wir[0], ir[j]);  ir[j]  = fmaf(mv.y, wir[1], ir[j]);
            ir[j]  = fmaf(mv.z, wir[2], ir[j]);  ir[j]  = fmaf(mv.w, wir[3], ir[j]);
            iz[j]  = fmaf(mv.x, wiz[0], iz[j]);  iz[j]  = fmaf(mv.y, wiz[1], iz[j]);
            iz[j]  = fmaf(mv.z, wiz[2], iz[j]);  iz[j]  = fmaf(mv.w, wiz[3], iz[j]);
            inn[j] = fmaf(mv.x, win[0], inn[j]); inn[j] = fmaf(mv.y, win[1], inn[j]);
            inn[j] = fmaf(mv.z, win[2], inn[j]); inn[j] = fmaf(mv.w, win[3], inn[j]);
            hr[j]  = fmaf(hv.x, whr[0], hr[j]);  hr[j]  = fmaf(hv.y, whr[1], hr[j]);
            hr[j]  = fmaf(hv.z, whr[2], hr[j]);  hr[j]  = fmaf(hv.w, whr[3], hr[j]);
            hz[j]  = fmaf(hv.x, whz[0], hz[j]);  hz[j]  = fmaf(hv.y, whz[1], hz[j]);
            hz[j]  = fmaf(hv.z, whz[2], hz[j]);  hz[j]  = fmaf(hv.w, whz[3], hz[j]);
            hn[j]  = fmaf(hv.x, whn[0], hn[j]);  hn[j]  = fmaf(hv.y, whn[1], hn[j]);
            hn[j]  = fmaf(hv.z, whn[2], hn[j]);  hn[j]  = fmaf(hv.w, whn[3], hn[j]);
        }
    }
    const float bir = bih[c], biz = bih[64 + c], bin = bih[128 + c];
    const float bhr = bhh[c], bhz = bhh[64 + c], bhn = bhh[128 + c];
    #pragma unroll
    for (int j = 0; j < 8; ++j) {
        const int n = n0 + j * 4 + tg;
        const float r  = 1.f / (1.f + __expf(-((ir[j] + bir) + (hr[j] + bhr))));
        const float zg = 1.f / (1.f + __expf(-((iz[j] + biz) + (hz[j] + bhz))));
        const float ng = tanhf((inn[j] + bin) + r * (hn[j] + bhn));
        h[(size_t)n * 64 + c] = (1.f - zg) * ng + zg * hs[j * 4 + tg][c];
    }
}

// ---------------- first-node-per-graph indices (searchsorted) ----------------
__global__ void k_idx(const int* __restrict__ batch, int* __restrict__ idx) {
    int g = threadIdx.x;
    if (g >= NGRAPH) return;
    int lo = 0, hi = NN;
    while (lo < hi) {
        int mid = (lo + hi) >> 1;
        if (batch[mid] < g) lo = mid + 1; else hi = mid;
    }
    idx[g] = lo;
}

// ---------------- readout head: all weights/activations in LDS ----------------
__global__ void k_head(const float* __restrict__ h, const int* __restrict__ idx,
                       const float* __restrict__ fcsw, const float* __restrict__ fcsb,
                       const float* __restrict__ f2cw, const float* __restrict__ f2cb,
                       const float* __restrict__ f3cw, const float* __restrict__ f3cb,
                       const float* __restrict__ f2dw, const float* __restrict__ f2db,
                       const float* __restrict__ f3dw, const float* __restrict__ f3db,
                       float* __restrict__ out) {
    __shared__ float hsB[4096];  // hsel -> xgs
    __shared__ float waB[4096];  // fcsw -> xcs
    __shared__ float wbB[4096];  // f2cw -> xds
    __shared__ float wcB[4096];  // f2dw -> f3 weights
    const int tid = threadIdx.x;
    for (int i = tid; i < 4096; i += 256) {
        int g = i >> 6, k = i & 63;
        hsB[i] = h[(size_t)idx[g] * 64 + k];
        waB[i] = fcsw[i];
        wbB[i] = f2cw[i];
        wcB[i] = f2dw[i];
    }
    __syncthreads();
    float v[16];
    #pragma unroll
    for (int j = 0; j < 16; ++j) {
        const int i = j * 256 + tid, g = i >> 6, c = i & 63;
        float a = fcsb[c];
        for (int k = 0; k < 64; ++k) a = fmaf(hsB[g * 64 + k], waB[k * 64 + c], a);
        v[j] = fmaxf(a, 0.f);
    }
    __syncthreads();
    #pragma unroll
    for (int j = 0; j < 16; ++j) hsB[j * 256 + tid] = v[j];   // xgs
    __syncthreads();
    float vc[16], vd[16];
    #pragma unroll
    for (int j = 0; j < 16; ++j) {
        const int i = j * 256 + tid, g = i >> 6, c = i & 63;
        float a1 = f2cb[c], a2 = f2db[c];
        for (int k = 0; k < 64; ++k) {
            const float xv = hsB[g * 64 + k];
            a1 = fmaf(xv, wbB[k * 64 + c], a1);
            a2 = fmaf(xv, wcB[k * 64 + c], a2);
        }
        vc[j] = fmaxf(a1, 0.f);
        vd[j] = fmaxf(a2, 0.f);
    }
    __syncthreads();
    #pragma unroll
    for (int j = 0; j < 16; ++j) {
        waB[j * 256 + tid] = vc[j];   // xcs
        wbB[j * 256 + tid] = vd[j];   // xds
    }
    if (tid < 128) wcB[tid] = f3cw[tid];
    else           wcB[tid] = f3dw[tid - 128];
    __syncthreads();
    if (tid < 128) {
        int g = tid >> 1, j = tid & 1;
        float a = f3cb[j];
        for (int k = 0; k < 64; ++k) a = fmaf(waB[g * 64 + k], wcB[k * 2 + j], a);
        out[g * 2 + j] = 1.f / (1.f + expf(-a));
    } else {
        int t = tid - 128, g = t >> 1, j = t & 1;
        float a = f3db[j];
        for (int k = 0; k < 64; ++k) a = fmaf(wbB[g * 64 + k], wcB[128 + k * 2 + j], a);
        out[128 + g * 2 + j] = a;
    }
}

// ---------------- host launcher ----------------
extern "C" void kernel_launch(void* const* d_in, const int* in_sizes, int n_in,
                              void* d_out, int out_size, void* d_ws, size_t ws_size,
                              hipStream_t stream) {
    (void)in_sizes; (void)n_in; (void)out_size; (void)ws_size;
    const float* x    = (const float*)d_in[0];
    const int* ei1    = (const int*)d_in[1];
    const int* ei2    = (const int*)d_in[2];
    const float* w1   = (const float*)d_in[3];
    const float* w2   = (const float*)d_in[4];
    const int* batch  = (const int*)d_in[5];
    const float* fc1w = (const float*)d_in[6];
    const float* fc1b = (const float*)d_in[7];
    const float* lfw  = (const float*)d_in[8];
    const float* lfb  = (const float*)d_in[9];
    const float* lsw  = (const float*)d_in[10];
    const float* lsb  = (const float*)d_in[11];
    const float* wih  = (const float*)d_in[12];
    const float* bih  = (const float*)d_in[13];
    const float* whh  = (const float*)d_in[14];
    const float* bhh  = (const float*)d_in[15];
    const float* fcsw = (const float*)d_in[16];
    const float* fcsb = (const float*)d_in[17];
    const float* f2cw = (const float*)d_in[18];
    const float* f2cb = (const float*)d_in[19];
    const float* f3cw = (const float*)d_in[20];
    const float* f3cb = (const float*)d_in[21];
    const float* f2dw = (const float*)d_in[22];
    const float* f2db = (const float*)d_in[23];
    const float* f3dw = (const float*)d_in[24];
    const float* f3db = (const float*)d_in[25];

    char* ws = (char*)d_ws;
    size_t off = 0;
    auto alloc = [&](size_t bytes) { char* p = ws + off; off += (bytes + 255) & ~size_t(255); return p; };
    float*   Pi    = (float*)alloc(size_t(NN) * 128 * 4);      // 20.5 MB
    __half2* Pj16  = (__half2*)alloc(size_t(NN) * 64 * 4);     // 10.2 MB
    float*   hbuf  = (float*)alloc(size_t(NN) * CD * 4);
    float*   mbuf  = (float*)alloc(size_t(NN) * CD * 4);
    int*   cnt1  = (int*)alloc(size_t(NN) * 4);
    int*   cnt2  = (int*)alloc(size_t(NN) * 4);
    int*   rs1   = (int*)alloc(size_t(NN + 1) * 4);
    int*   rs2   = (int*)alloc(size_t(NN + 1) * 4);
    int*   cur1  = (int*)alloc(size_t(NN + 1) * 4);
    int*   cur2  = (int*)alloc(size_t(NN + 1) * 4);
    int*   perm1 = (int*)alloc(size_t(NE) * 4);
    int*   perm2 = (int*)alloc(size_t(NE) * 4);
    int2*  rcP1  = (int2*)alloc(size_t(NE) * 8);
    int2*  rcP2  = (int2*)alloc(size_t(NE) * 8);
    float4* ewP1 = (float4*)alloc(size_t(NE) * 16);
    float4* ewP2 = (float4*)alloc(size_t(NE) * 16);
    int*   part1 = (int*)alloc(256 * 4);
    int*   part2 = (int*)alloc(256 * 4);
    int*   offs1 = (int*)alloc(256 * 4);
    int*   offs2 = (int*)alloc(256 * 4);
    int*   idx   = (int*)alloc(256);

    const int NB_NC = (NN * CD + 255) / 256;
    const int NB_E  = (NE + 255) / 256;
    const int EDGE_BLOCKS = NN / 8;    // 5000 row-range blocks
    const int PROJ_BLOCKS = NN / 8;    // 5000
    const int GRU_BLOCKS  = NN / 32;   // 1250

    const float* lfe = lfw + 128 * 64;
    const float* lse = lsw + 128 * 64;

    // CSR build (parallel scan) + packed edge pre-gather
    hipMemsetAsync(cnt1, 0, size_t(NN) * 4, stream);
    hipMemsetAsync(cnt2, 0, size_t(NN) * 4, stream);
    k_count<<<NB_E, 256, 0, stream>>>(ei1, cnt1);
    k_count<<<NB_E, 256, 0, stream>>>(ei2, cnt2);
    k_scan_part<<<SCAN_BLOCKS, 256, 0, stream>>>(cnt1, part1);
    k_scan_part<<<SCAN_BLOCKS, 256, 0, stream>>>(cnt2, part2);
    k_scan_mid<<<1, 256, 0, stream>>>(part1, offs1, SCAN_BLOCKS);
    k_scan_mid<<<1, 256, 0, stream>>>(part2, offs2, SCAN_BLOCKS);
    k_scan_fill<<<SCAN_BLOCKS, 256, 0, stream>>>(cnt1, offs1, rs1, cur1);
    k_scan_fill<<<SCAN_BLOCKS, 256, 0, stream>>>(cnt2, offs2, rs2, cur2);
    k_scatter<<<NB_E, 256, 0, stream>>>(ei1, cur1, perm1);
    k_scatter<<<NB_E, 256, 0, stream>>>(ei2, cur2, perm2);
    k_edge_gather<<<NB_E, 256, 0, stream>>>(ei1, w1, perm1, rcP1, ewP1);
    k_edge_gather<<<NB_E, 256, 0, stream>>>(ei2, w2, perm2, rcP2, ewP2);

    k_fc1<<<NB_NC, 256, 0, stream>>>(x, fc1w, fc1b, hbuf);

    for (int it = 0; it < 3; ++it) {
        k_proj<<<PROJ_BLOCKS, 256, 0, stream>>>(hbuf, lfw, lfb, lsw, lsb, Pi, Pj16);
        k_edge_range<<<EDGE_BLOCKS, 256, 0, stream>>>(Pj16, Pi, rcP2, ewP2,
                                                      lfe, lse, rs2, hbuf, mbuf);
        k_proj<<<PROJ_BLOCKS, 256, 0, stream>>>(mbuf, lfw, lfb, lsw, lsb, Pi, Pj16);
        k_edge_range<<<EDGE_BLOCKS, 256, 0, stream>>>(Pj16, Pi, rcP1, ewP1,
                                                      lfe, lse, rs1, mbuf, mbuf);
        k_gru_fused<<<GRU_BLOCKS, 256, 0, stream>>>(mbuf, hbuf, wih, bih, whh, bhh);
    }

    k_idx<<<1, 64, 0, stream>>>(batch, idx);
    k_head<<<1, 256, 0, stream>>>(hbuf, idx, fcsw, fcsb, f2cw, f2cb, f3cw, f3cb,
                                  f2dw, f2db, f3dw, f3db, (float*)d_out);
}

// Round 16
// 734.473 us; speedup vs baseline: 1.0745x; 1.0043x over previous
//
#include <hip/hip_runtime.h>
#include <hip/hip_bf16.h>
#include <hip/hip_fp16.h>
#include <math.h>

constexpr int NE = 400000;
constexpr int NN = 40000;
constexpr int CD = 64;
constexpr int NGRAPH = 64;
constexpr int SCAN_BLOCKS = (NN + 255) / 256;   // 157

// ---------------- fc1: x0 = relu(x @ fc1_w + b) ----------------
__global__ void k_fc1(const float* __restrict__ x,
                      const float* __restrict__ w,
                      const float* __restrict__ b,
                      float* __restrict__ out) {
    int i = blockIdx.x * 256 + threadIdx.x;
    if (i >= NN * CD) return;
    int n = i >> 6, c = i & 63;
    float acc = b[c];
    #pragma unroll
    for (int k = 0; k < 9; ++k)
        acc = fmaf(x[n * 9 + k], w[k * 64 + c], acc);
    out[i] = fmaxf(acc, 0.f);
}

// ---------------- edge counts ----------------
__global__ void k_count(const int* __restrict__ ei, int* __restrict__ cnt) {
    int e = blockIdx.x * 256 + threadIdx.x;
    if (e >= NE) return;
    atomicAdd(&cnt[ei[e]], 1);
}

// ---------------- parallel scan, phase 1: per-block partial sums ----------------
__global__ void k_scan_part(const int* __restrict__ cnt, int* __restrict__ partials) {
    __shared__ int red[256];
    const int tid = threadIdx.x;
    const int i = blockIdx.x * 256 + tid;
    red[tid] = (i < NN) ? cnt[i] : 0;
    __syncthreads();
    for (int s = 128; s > 0; s >>= 1) {
        if (tid < s) red[tid] += red[tid + s];
        __syncthreads();
    }
    if (tid == 0) partials[blockIdx.x] = red[0];
}

// ---------------- phase 2: single-block scan of partials (nblk <= 256) ----------------
__global__ void k_scan_mid(const int* __restrict__ partials, int* __restrict__ offs, int nblk) {
    __shared__ int part[256];
    const int tid = threadIdx.x;
    const int v = (tid < nblk) ? partials[tid] : 0;
    part[tid] = v;
    __syncthreads();
    for (int off = 1; off < 256; off <<= 1) {
        int t = (tid >= off) ? part[tid - off] : 0;
        __syncthreads();
        part[tid] += t;
        __syncthreads();
    }
    if (tid < nblk) offs[tid] = part[tid] - v;   // exclusive
}

// ---------------- phase 3: in-block exclusive scan + base -> row_start, cursor ----------------
__global__ void k_scan_fill(const int* __restrict__ cnt, const int* __restrict__ offs,
                            int* __restrict__ row_start, int* __restrict__ cursor) {
    __shared__ int part[256];
    const int tid = threadIdx.x;
    const int i = blockIdx.x * 256 + tid;
    const int v = (i < NN) ? cnt[i] : 0;
    part[tid] = v;
    __syncthreads();
    for (int off = 1; off < 256; off <<= 1) {
        int t = (tid >= off) ? part[tid - off] : 0;
        __syncthreads();
        part[tid] += t;
        __syncthreads();
    }
    const int excl = part[tid] - v + offs[blockIdx.x];
    if (i < NN) { row_start[i] = excl; cursor[i] = excl; }
    if (i == NN - 1) row_start[NN] = NE;
}

// ---------------- scatter edge ids into CSR order ----------------
__global__ void k_scatter(const int* __restrict__ ei, int* __restrict__ cursor,
                          int* __restrict__ perm) {
    int e = blockIdx.x * 256 + threadIdx.x;
    if (e >= NE) return;
    int pos = atomicAdd(&cursor[ei[e]], 1);
    perm[pos] = e;
}

// ---------------- pre-gather packed edge data into CSR order ----------------
__global__ void k_edge_gather(const int* __restrict__ ei, const float* __restrict__ ew,
                              const int* __restrict__ perm,
                              int2* __restrict__ rcP, float4* __restrict__ ewP) {
    int p = blockIdx.x * 256 + threadIdx.x;
    if (p >= NE) return;
    const int e = perm[p];
    rcP[p] = make_int2(ei[e], ei[NE + e]);
    ewP[p] = make_float4(ew[3 * e], ew[3 * e + 1], ew[3 * e + 2], 0.f);
}

// ---------------- node projection, split output:
// Pi[n][0:64]  = bf + x@Wf_top, Pi[n][64:128] = bs + x@Ws_top  (row-side, f32)
// Pj16[n][c] = half2(x@Wf_bot[c], x@Ws_bot[c])                 (col-side, gathered)
__global__ void k_proj(const float* __restrict__ x,
                       const float* __restrict__ wf, const float* __restrict__ bfp,
                       const float* __restrict__ wsp, const float* __restrict__ bsp,
                       float* __restrict__ Pi, __half2* __restrict__ Pj16) {
    __shared__ __align__(16) float xs[8][64];
    __shared__ float sS[8][64];
    const int tid = threadIdx.x;
    const int n0 = blockIdx.x * 8;
    for (int i = tid; i < 512; i += 256)
        xs[i >> 6][i & 63] = x[(size_t)(n0 + (i >> 6)) * 64 + (i & 63)];
    __syncthreads();
    const int q = tid >> 6, c = tid & 63;
    const float* __restrict__ wp = ((q & 2) ? wsp : wf) + ((q & 1) ? 64 * 64 : 0) + c;
    const float bias = (q == 0) ? bfp[c] : (q == 2 ? bsp[c] : 0.f);
    float acc[8];
    #pragma unroll
    for (int g = 0; g < 8; ++g) acc[g] = bias;
    for (int k4 = 0; k4 < 64; k4 += 4) {
        const float w0 = wp[(k4 + 0) * 64];
        const float w1 = wp[(k4 + 1) * 64];
        const float w2 = wp[(k4 + 2) * 64];
        const float w3 = wp[(k4 + 3) * 64];
        #pragma unroll
        for (int g = 0; g < 8; ++g) {
            const float4 xv = *(const float4*)&xs[g][k4];
            acc[g] = fmaf(xv.x, w0, acc[g]);
            acc[g] = fmaf(xv.y, w1, acc[g]);
            acc[g] = fmaf(xv.z, w2, acc[g]);
            acc[g] = fmaf(xv.w, w3, acc[g]);
        }
    }
    if (q == 3) {
        #pragma unroll
        for (int g = 0; g < 8; ++g) sS[g][c] = acc[g];
    }
    __syncthreads();
    #pragma unroll
    for (int g = 0; g < 8; ++g) {
        const size_t n = n0 + g;
        if (q == 0)      Pi[n * 128 + c]      = acc[g];
        else if (q == 2) Pi[n * 128 + 64 + c] = acc[g];
        else if (q == 1) Pj16[n * 64 + c]     = __floats2half2_rn(acc[g], sS[g][c]);
    }
}

// ---------------- edge-parallel row-range conv: 8 rows/block,
//                  2 channels/lane -> half-wave = edge; int32 indexing ----------------
__launch_bounds__(256, 7)
__global__ void k_edge_range(const __half2* __restrict__ Pj,
                             const float* __restrict__ Pi,
                             const int2* __restrict__ rcP, const float4* __restrict__ ewP,
                             const float* __restrict__ wfe, const float* __restrict__ wse,
                             const int* __restrict__ rs,
                             const float* __restrict__ xin, float* __restrict__ out) {
    __shared__ __align__(16) float piS[8][128];     // 4 KB
    __shared__ __align__(16) float accS[8][8][64];  // 16 KB: [half-wave][row][ch]
    __shared__ int rsS[9];
    const int tid = threadIdx.x;
    const int hw = tid >> 5;            // half-wave 0..7 (one edge each per pass)
    const int c2 = (tid & 31) * 2;      // channel pair base
    const int r0 = blockIdx.x * 8;
    for (int i = tid; i < 1024; i += 256)
        piS[i >> 7][i & 127] = Pi[(size_t)r0 * 128 + i];
    for (int i = tid; i < 4096; i += 256)
        ((float*)accS)[i] = 0.f;
    if (tid < 9) rsS[tid] = rs[r0 + tid];
    __syncthreads();
    const float wf0a = wfe[c2],       wf0b = wfe[c2 + 1];
    const float wf1a = wfe[64 + c2],  wf1b = wfe[64 + c2 + 1];
    const float wf2a = wfe[128 + c2], wf2b = wfe[128 + c2 + 1];
    const float ws0a = wse[c2],       ws0b = wse[c2 + 1];
    const float ws1a = wse[64 + c2],  ws1b = wse[64 + c2 + 1];
    const float ws2a = wse[128 + c2], ws2b = wse[128 + c2 + 1];
    const int pbeg = rsS[0], pend = rsS[8];
    #pragma unroll 4
    for (int p = pbeg + hw; p < pend; p += 8) {
        const int2 rc = rcP[p];
        const float4 e = ewP[p];
        const uint2 Jraw = *(const uint2*)&Pj[rc.y * 64 + c2];   // 8B: channels c2,c2+1
        const float2 Ja = __half22float2(*(const __half2*)&Jraw.x);
        const float2 Jb = __half22float2(*(const __half2*)&Jraw.y);
        const int row = rc.x - r0;
        const float2 pf = *(const float2*)&piS[row][c2];
        const float2 ps = *(const float2*)&piS[row][64 + c2];
        const float afa = pf.x + Ja.x + e.x * wf0a + e.y * wf1a + e.z * wf2a;
        const float asa = ps.x + Ja.y + e.x * ws0a + e.y * ws1a + e.z * ws2a;
        const float afb = pf.y + Jb.x + e.x * wf0b + e.y * wf1b + e.z * wf2b;
        const float asb = ps.y + Jb.y + e.x * ws0b + e.y * ws1b + e.z * ws2b;
        const float sga = 1.f / (1.f + __expf(-afa));
        const float spa = (asa > 20.f) ? asa : __logf(1.f + __expf(asa));
        const float sgb = 1.f / (1.f + __expf(-afb));
        const float spb = (asb > 20.f) ? asb : __logf(1.f + __expf(asb));
        float2 acc = *(const float2*)&accS[hw][row][c2];
        acc.x = fmaf(sga, spa, acc.x);
        acc.y = fmaf(sgb, spb, acc.y);
        *(float2*)&accS[hw][row][c2] = acc;
    }
    __syncthreads();
    for (int i = tid; i < 512; i += 256) {
        const int row = i >> 6, ch = i & 63;
        float s = 0.f;
        #pragma unroll
        for (int a = 0; a < 8; ++a) s += accS[a][row][ch];
        const int deg = rsS[row + 1] - rsS[row];
        const size_t o = (size_t)(r0 + row) * 64 + ch;
        out[o] = fmaxf(fmaf(s, 1.f / (float)max(deg, 1), xin[o]), 0.f);
    }
}

// ---------------- fused GRU: h = GRU(m, h), weights from L2 ----------------
__global__ void k_gru_fused(const float* __restrict__ m, float* __restrict__ h,
                            const float* __restrict__ wih, const float* __restrict__ bih,
                            const float* __restrict__ whh, const float* __restrict__ bhh) {
    __shared__ __align__(16) float ms[32][64];
    __shared__ __align__(16) float hs[32][64];
    const int tid = threadIdx.x;
    const int n0 = blockIdx.x * 32;
    for (int i = tid; i < 2048; i += 256) {
        ms[i >> 6][i & 63] = m[(size_t)n0 * 64 + i];
        hs[i >> 6][i & 63] = h[(size_t)n0 * 64 + i];
    }
    __syncthreads();
    const int c = tid & 63, tg = tid >> 6;
    float ir[8], iz[8], inn[8], hr[8], hz[8], hn[8];
    #pragma unroll
    for (int j = 0; j < 8; ++j) { ir[j]=0.f; iz[j]=0.f; inn[j]=0.f; hr[j]=0.f; hz[j]=0.f; hn[j]=0.f; }
    for (int k4 = 0; k4 < 64; k4 += 4) {
        float wir[4], wiz[4], win[4], whr[4], whz[4], whn[4];
        #pragma unroll
        for (int u = 0; u < 4; ++u) {
            const int k = k4 + u;
            wir[u] = wih[k * 192 + c];
            wiz[u] = wih[k * 192 + 64 + c];
            win[u] = wih[k * 192 + 128 + c];
            whr[u] = whh[k * 192 + c];
            whz[u] = whh[k * 192 + 64 + c];
            whn[u] = whh[k * 192 + 128 + c];
        }
        #pragma unroll
        for (int j = 0; j < 8; ++j) {
            const int nrow = j * 4 + tg;
            const float4 mv = *(const float4*)&ms[nrow][k4];
            const float4 hv = *(const float4*)&hs[nrow][k4];
            ir[j]  = fmaf(mv.x, wir[0], ir[j]);  ir[j]  = fmaf(mv.y, wir[1], ir[j]);
            ir[j]  = fmaf(mv.z, wir[2], ir[j]);  ir[j]  = fmaf(mv.w, wir[3], ir[j]);
            iz[j]  = fmaf(mv.x, wiz[0], iz[j]);  iz[j]  = fmaf(mv.y, wiz[1], iz[j]);
            iz[j]  = fmaf(mv.z, wiz[2], iz[j]);  iz[j]  = fmaf(mv.w, wiz[3], iz[j]);
            inn[j] = fmaf(mv.x, win[0], inn[j]); inn[j] = fmaf(mv.y, win[1], inn[j]);
            inn[j] = fmaf(mv.z, win[2], inn[j]); inn[j] = fmaf(mv.w, win[3], inn[j]);
            hr[j]  = fmaf(hv.x, whr[0], hr[j]);  hr[j]  = fmaf(hv.y, whr[1], hr[j]);
            hr[j]  = fmaf(hv.z, whr[2], hr[j]);  hr[j]  = fmaf(hv.w, whr[3], hr[j]);
            hz[j]  = fmaf(hv.x, whz[0], hz[j]);  hz[j]  = fmaf(hv.y, whz[1], hz[j]);
            hz[j]  = fmaf(hv.z, whz[2], hz[j]);  hz[j]  = fmaf(hv.w, whz[3], hz[j]);
            hn[j]  = fmaf(hv.x, whn[0], hn[j]);  hn[j]  = fmaf(hv.y, whn[1], hn[j]);
            hn[j]  = fmaf(hv.z, whn[2], hn[j]);  hn[j]  = fmaf(hv.w, whn[3], hn[j]);
        }
    }
    const float bir = bih[c], biz = bih[64 + c], bin = bih[128 + c];
    const float bhr = bhh[c], bhz = bhh[64 + c], bhn = bhh[128 + c];
    #pragma unroll
    for (int j = 0; j < 8; ++j) {
        const int n = n0 + j * 4 + tg;
        const float r  = 1.f / (1.f + __expf(-((ir[j] + bir) + (hr[j] + bhr))));
        const float zg = 1.f / (1.f + __expf(-((iz[j] + biz) + (hz[j] + bhz))));
        const float ng = tanhf((inn[j] + bin) + r * (hn[j] + bhn));
        h[(size_t)n * 64 + c] = (1.f - zg) * ng + zg * hs[j * 4 + tg][c];
    }
}

// ---------------- first-node-per-graph indices (searchsorted) ----------------
__global__ void k_idx(const int* __restrict__ batch, int* __restrict__ idx) {
    int g = threadIdx.x;
    if (g >= NGRAPH) return;
    int lo = 0, hi = NN;
    while (lo < hi) {
        int mid = (lo + hi) >> 1;
        if (batch[mid] < g) lo = mid + 1; else hi = mid;
    }
    idx[g] = lo;
}

// ---------------- readout head: all weights/activations in LDS ----------------
__global__ void k_head(const float* __restrict__ h, const int* __restrict__ idx,
                       const float* __restrict__ fcsw, const float* __restrict__ fcsb,
                       const float* __restrict__ f2cw, const float* __restrict__ f2cb,
                       const float* __restrict__ f3cw, const float* __restrict__ f3cb,
                       const float* __restrict__ f2dw, const float* __restrict__ f2db,
                       const float* __restrict__ f3dw, const float* __restrict__ f3db,
                       float* __restrict__ out) {
    __shared__ float hsB[4096];  // hsel -> xgs
    __shared__ float waB[4096];  // fcsw -> xcs
    __shared__ float wbB[4096];  // f2cw -> xds
    __shared__ float wcB[4096];  // f2dw -> f3 weights
    const int tid = threadIdx.x;
    for (int i = tid; i < 4096; i += 256) {
        int g = i >> 6, k = i & 63;
        hsB[i] = h[(size_t)idx[g] * 64 + k];
        waB[i] = fcsw[i];
        wbB[i] = f2cw[i];
        wcB[i] = f2dw[i];
    }
    __syncthreads();
    float v[16];
    #pragma unroll
    for (int j = 0; j < 16; ++j) {
        const int i = j * 256 + tid, g = i >> 6, c = i & 63;
        float a = fcsb[c];
        for (int k = 0; k < 64; ++k) a = fmaf(hsB[g * 64 + k], waB[k * 64 + c], a);
        v[j] = fmaxf(a, 0.f);
    }
    __syncthreads();
    #pragma unroll
    for (int j = 0; j < 16; ++j) hsB[j * 256 + tid] = v[j];   // xgs
    __syncthreads();
    float vc[16], vd[16];
    #pragma unroll
    for (int j = 0; j < 16; ++j) {
        const int i = j * 256 + tid, g = i >> 6, c = i & 63;
        float a1 = f2cb[c], a2 = f2db[c];
        for (int k = 0; k < 64; ++k) {
            const float xv = hsB[g * 64 + k];
            a1 = fmaf(xv, wbB[k * 64 + c], a1);
            a2 = fmaf(xv, wcB[k * 64 + c], a2);
        }
        vc[j] = fmaxf(a1, 0.f);
        vd[j] = fmaxf(a2, 0.f);
    }
    __syncthreads();
    #pragma unroll
    for (int j = 0; j < 16; ++j) {
        waB[j * 256 + tid] = vc[j];   // xcs
        wbB[j * 256 + tid] = vd[j];   // xds
    }
    if (tid < 128) wcB[tid] = f3cw[tid];
    else           wcB[tid] = f3dw[tid - 128];
    __syncthreads();
    if (tid < 128) {
        int g = tid >> 1, j = tid & 1;
        float a = f3cb[j];
        for (int k = 0; k < 64; ++k) a = fmaf(waB[g * 64 + k], wcB[k * 2 + j], a);
        out[g * 2 + j] = 1.f / (1.f + expf(-a));
    } else {
        int t = tid - 128, g = t >> 1, j = t & 1;
        float a = f3db[j];
        for (int k = 0; k < 64; ++k) a = fmaf(wbB[g * 64 + k], wcB[128 + k * 2 + j], a);
        out[128 + g * 2 + j] = a;
    }
}

// ---------------- host launcher ----------------
extern "C" void kernel_launch(void* const* d_in, const int* in_sizes, int n_in,
                              void* d_out, int out_size, void* d_ws, size_t ws_size,
                              hipStream_t stream) {
    (void)in_sizes; (void)n_in; (void)out_size; (void)ws_size;
    const float* x    = (const float*)d_in[0];
    const int* ei1    = (const int*)d_in[1];
    const int* ei2    = (const int*)d_in[2];
    const float* w1   = (const float*)d_in[3];
    const float* w2   = (const float*)d_in[4];
    const int* batch  = (const int*)d_in[5];
    const float* fc1w = (const float*)d_in[6];
    const float* fc1b = (const float*)d_in[7];
    const float* lfw  = (const float*)d_in[8];
    const float* lfb  = (const float*)d_in[9];
    const float* lsw  = (const float*)d_in[10];
    const float* lsb  = (const float*)d_in[11];
    const float* wih  = (const float*)d_in[12];
    const float* bih  = (const float*)d_in[13];
    const float* whh  = (const float*)d_in[14];
    const float* bhh  = (const float*)d_in[15];
    const float* fcsw = (const float*)d_in[16];
    const float* fcsb = (const float*)d_in[17];
    const float* f2cw = (const float*)d_in[18];
    const float* f2cb = (const float*)d_in[19];
    const float* f3cw = (const float*)d_in[20];
    const float* f3cb = (const float*)d_in[21];
    const float* f2dw = (const float*)d_in[22];
    const float* f2db = (const float*)d_in[23];
    const float* f3dw = (const float*)d_in[24];
    const float* f3db = (const float*)d_in[25];

    char* ws = (char*)d_ws;
    size_t off = 0;
    auto alloc = [&](size_t bytes) { char* p = ws + off; off += (bytes + 255) & ~size_t(255); return p; };
    float*   Pi    = (float*)alloc(size_t(NN) * 128 * 4);      // 20.5 MB
    __half2* Pj16  = (__half2*)alloc(size_t(NN) * 64 * 4);     // 10.2 MB
    float*   hbuf  = (float*)alloc(size_t(NN) * CD * 4);
    float*   mbuf  = (float*)alloc(size_t(NN) * CD * 4);
    int*   cnt1  = (int*)alloc(size_t(NN) * 4);
    int*   cnt2  = (int*)alloc(size_t(NN) * 4);
    int*   rs1   = (int*)alloc(size_t(NN + 1) * 4);
    int*   rs2   = (int*)alloc(size_t(NN + 1) * 4);
    int*   cur1  = (int*)alloc(size_t(NN + 1) * 4);
    int*   cur2  = (int*)alloc(size_t(NN + 1) * 4);
    int*   perm1 = (int*)alloc(size_t(NE) * 4);
    int*   perm2 = (int*)alloc(size_t(NE) * 4);
    int2*  rcP1  = (int2*)alloc(size_t(NE) * 8);
    int2*  rcP2  = (int2*)alloc(size_t(NE) * 8);
    float4* ewP1 = (float4*)alloc(size_t(NE) * 16);
    float4* ewP2 = (float4*)alloc(size_t(NE) * 16);
    int*   part1 = (int*)alloc(256 * 4);
    int*   part2 = (int*)alloc(256 * 4);
    int*   offs1 = (int*)alloc(256 * 4);
    int*   offs2 = (int*)alloc(256 * 4);
    int*   idx   = (int*)alloc(256);

    const int NB_NC = (NN * CD + 255) / 256;
    const int NB_E  = (NE + 255) / 256;
    const int EDGE_BLOCKS = NN / 8;    // 5000 row-range blocks
    const int PROJ_BLOCKS = NN / 8;    // 5000
    const int GRU_BLOCKS  = NN / 32;   // 1250

    const float* lfe = lfw + 128 * 64;
    const float* lse = lsw + 128 * 64;

    // CSR build (parallel scan) + packed edge pre-gather
    hipMemsetAsync(cnt1, 0, size_t(NN) * 4, stream);
    hipMemsetAsync(cnt2, 0, size_t(NN) * 4, stream);
    k_count<<<NB_E, 256, 0, stream>>>(ei1, cnt1);
    k_count<<<NB_E, 256, 0, stream>>>(ei2, cnt2);
    k_scan_part<<<SCAN_BLOCKS, 256, 0, stream>>>(cnt1, part1);
    k_scan_part<<<SCAN_BLOCKS, 256, 0, stream>>>(cnt2, part2);
    k_scan_mid<<<1, 256, 0, stream>>>(part1, offs1, SCAN_BLOCKS);
    k_scan_mid<<<1, 256, 0, stream>>>(part2, offs2, SCAN_BLOCKS);
    k_scan_fill<<<SCAN_BLOCKS, 256, 0, stream>>>(cnt1, offs1, rs1, cur1);
    k_scan_fill<<<SCAN_BLOCKS, 256, 0, stream>>>(cnt2, offs2, rs2, cur2);
    k_scatter<<<NB_E, 256, 0, stream>>>(ei1, cur1, perm1);
    k_scatter<<<NB_E, 256, 0, stream>>>(ei2, cur2, perm2);
    k_edge_gather<<<NB_E, 256, 0, stream>>>(ei1, w1, perm1, rcP1, ewP1);
    k_edge_gather<<<NB_E, 256, 0, stream>>>(ei2, w2, perm2, rcP2, ewP2);

    k_fc1<<<NB_NC, 256, 0, stream>>>(x, fc1w, fc1b, hbuf);

    for (int it = 0; it < 3; ++it) {
        k_proj<<<PROJ_BLOCKS, 256, 0, stream>>>(hbuf, lfw, lfb, lsw, lsb, Pi, Pj16);
        k_edge_range<<<EDGE_BLOCKS, 256, 0, stream>>>(Pj16, Pi, rcP2, ewP2,
                                                      lfe, lse, rs2, hbuf, mbuf);
        k_proj<<<PROJ_BLOCKS, 256, 0, stream>>>(mbuf, lfw, lfb, lsw, lsb, Pi, Pj16);
        k_edge_range<<<EDGE_BLOCKS, 256, 0, stream>>>(Pj16, Pi, rcP1, ewP1,
                                                      lfe, lse, rs1, mbuf, mbuf);
        k_gru_fused<<<GRU_BLOCKS, 256, 0, stream>>>(mbuf, hbuf, wih, bih, whh, bhh);
    }

    k_idx<<<1, 64, 0, stream>>>(batch, idx);
    k_head<<<1, 256, 0, stream>>>(hbuf, idx, fcsw, fcsb, f2cw, f2cb, f3cw, f3cb,
                                  f2dw, f2db, f3dw, f3db, (float*)d_out);
}

// Round 17
// 728.357 us; speedup vs baseline: 1.0835x; 1.0084x over previous
//
#include <hip/hip_runtime.h>
#include <hip/hip_bf16.h>
#include <hip/hip_fp16.h>
#include <math.h>

constexpr int NE = 400000;
constexpr int NN = 40000;
constexpr int CD = 64;
constexpr int NGRAPH = 64;
constexpr int SCAN_BLOCKS = (NN + 255) / 256;   // 157
constexpr int EBLK = (NE + 255) / 256;          // 1563

// ---------------- fc1: x0 = relu(x @ fc1_w + b) ----------------
__global__ void k_fc1(const float* __restrict__ x,
                      const float* __restrict__ w,
                      const float* __restrict__ b,
                      float* __restrict__ out) {
    int i = blockIdx.x * 256 + threadIdx.x;
    if (i >= NN * CD) return;
    int n = i >> 6, c = i & 63;
    float acc = b[c];
    #pragma unroll
    for (int k = 0; k < 9; ++k)
        acc = fmaf(x[n * 9 + k], w[k * 64 + c], acc);
    out[i] = fmaxf(acc, 0.f);
}

// ---------------- edge counts, both sets ----------------
__global__ void k_count2(const int* __restrict__ ei1, const int* __restrict__ ei2,
                         int* __restrict__ cnt1, int* __restrict__ cnt2) {
    const int b = blockIdx.x;
    const bool s2 = (b >= EBLK);
    const int* ei = s2 ? ei2 : ei1;
    int* cnt = s2 ? cnt2 : cnt1;
    int e = (s2 ? b - EBLK : b) * 256 + threadIdx.x;
    if (e >= NE) return;
    atomicAdd(&cnt[ei[e]], 1);
}

// ---------------- parallel scan phase 1, both sets ----------------
__global__ void k_scan_part2(const int* __restrict__ cnt1, const int* __restrict__ cnt2,
                             int* __restrict__ part1, int* __restrict__ part2) {
    __shared__ int red[256];
    const int b = blockIdx.x;
    const bool s2 = (b >= SCAN_BLOCKS);
    const int* cnt = s2 ? cnt2 : cnt1;
    int* partials = s2 ? part2 : part1;
    const int bb = s2 ? b - SCAN_BLOCKS : b;
    const int tid = threadIdx.x;
    const int i = bb * 256 + tid;
    red[tid] = (i < NN) ? cnt[i] : 0;
    __syncthreads();
    for (int s = 128; s > 0; s >>= 1) {
        if (tid < s) red[tid] += red[tid + s];
        __syncthreads();
    }
    if (tid == 0) partials[bb] = red[0];
}

// ---------------- phase 2, both sets (2 blocks) ----------------
__global__ void k_scan_mid2(const int* __restrict__ part1, const int* __restrict__ part2,
                            int* __restrict__ offs1, int* __restrict__ offs2) {
    __shared__ int part[256];
    const bool s2 = (blockIdx.x == 1);
    const int* partials = s2 ? part2 : part1;
    int* offs = s2 ? offs2 : offs1;
    const int tid = threadIdx.x;
    const int v = (tid < SCAN_BLOCKS) ? partials[tid] : 0;
    part[tid] = v;
    __syncthreads();
    for (int off = 1; off < 256; off <<= 1) {
        int t = (tid >= off) ? part[tid - off] : 0;
        __syncthreads();
        part[tid] += t;
        __syncthreads();
    }
    if (tid < SCAN_BLOCKS) offs[tid] = part[tid] - v;
}

// ---------------- phase 3, both sets ----------------
__global__ void k_scan_fill2(const int* __restrict__ cnt1, const int* __restrict__ cnt2,
                             const int* __restrict__ offs1, const int* __restrict__ offs2,
                             int* __restrict__ rs1, int* __restrict__ rs2,
                             int* __restrict__ cur1, int* __restrict__ cur2) {
    __shared__ int part[256];
    const int b = blockIdx.x;
    const bool s2 = (b >= SCAN_BLOCKS);
    const int* cnt = s2 ? cnt2 : cnt1;
    const int* offs = s2 ? offs2 : offs1;
    int* row_start = s2 ? rs2 : rs1;
    int* cursor = s2 ? cur2 : cur1;
    const int bb = s2 ? b - SCAN_BLOCKS : b;
    const int tid = threadIdx.x;
    const int i = bb * 256 + tid;
    const int v = (i < NN) ? cnt[i] : 0;
    part[tid] = v;
    __syncthreads();
    for (int off = 1; off < 256; off <<= 1) {
        int t = (tid >= off) ? part[tid - off] : 0;
        __syncthreads();
        part[tid] += t;
        __syncthreads();
    }
    const int excl = part[tid] - v + offs[bb];
    if (i < NN) { row_start[i] = excl; cursor[i] = excl; }
    if (i == NN - 1) row_start[NN] = NE;
}

// ---------------- scatter, both sets ----------------
__global__ void k_scatter2(const int* __restrict__ ei1, const int* __restrict__ ei2,
                           int* __restrict__ cur1, int* __restrict__ cur2,
                           int* __restrict__ perm1, int* __restrict__ perm2) {
    const int b = blockIdx.x;
    const bool s2 = (b >= EBLK);
    const int* ei = s2 ? ei2 : ei1;
    int* cursor = s2 ? cur2 : cur1;
    int* perm = s2 ? perm2 : perm1;
    int e = (s2 ? b - EBLK : b) * 256 + threadIdx.x;
    if (e >= NE) return;
    int pos = atomicAdd(&cursor[ei[e]], 1);
    perm[pos] = e;
}

// ---------------- pre-gather packed edge data, both sets ----------------
__global__ void k_edge_gather2(const int* __restrict__ ei1, const int* __restrict__ ei2,
                               const float* __restrict__ w1, const float* __restrict__ w2,
                               const int* __restrict__ perm1, const int* __restrict__ perm2,
                               int2* __restrict__ rcP1, int2* __restrict__ rcP2,
                               float4* __restrict__ ewP1, float4* __restrict__ ewP2) {
    const int b = blockIdx.x;
    const bool s2 = (b >= EBLK);
    const int* ei = s2 ? ei2 : ei1;
    const float* ew = s2 ? w2 : w1;
    const int* perm = s2 ? perm2 : perm1;
    int2* rcP = s2 ? rcP2 : rcP1;
    float4* ewP = s2 ? ewP2 : ewP1;
    int p = (s2 ? b - EBLK : b) * 256 + threadIdx.x;
    if (p >= NE) return;
    const int e = perm[p];
    rcP[p] = make_int2(ei[e], ei[NE + e]);
    ewP[p] = make_float4(ew[3 * e], ew[3 * e + 1], ew[3 * e + 2], 0.f);
}

// ---------------- node projection (unchanged) ----------------
__global__ void k_proj(const float* __restrict__ x,
                       const float* __restrict__ wf, const float* __restrict__ bfp,
                       const float* __restrict__ wsp, const float* __restrict__ bsp,
                       float* __restrict__ Pi, __half2* __restrict__ Pj16) {
    __shared__ __align__(16) float xs[8][64];
    __shared__ float sS[8][64];
    const int tid = threadIdx.x;
    const int n0 = blockIdx.x * 8;
    for (int i = tid; i < 512; i += 256)
        xs[i >> 6][i & 63] = x[(size_t)(n0 + (i >> 6)) * 64 + (i & 63)];
    __syncthreads();
    const int q = tid >> 6, c = tid & 63;
    const float* __restrict__ wp = ((q & 2) ? wsp : wf) + ((q & 1) ? 64 * 64 : 0) + c;
    const float bias = (q == 0) ? bfp[c] : (q == 2 ? bsp[c] : 0.f);
    float acc[8];
    #pragma unroll
    for (int g = 0; g < 8; ++g) acc[g] = bias;
    for (int k4 = 0; k4 < 64; k4 += 4) {
        const float w0 = wp[(k4 + 0) * 64];
        const float w1 = wp[(k4 + 1) * 64];
        const float w2 = wp[(k4 + 2) * 64];
        const float w3 = wp[(k4 + 3) * 64];
        #pragma unroll
        for (int g = 0; g < 8; ++g) {
            const float4 xv = *(const float4*)&xs[g][k4];
            acc[g] = fmaf(xv.x, w0, acc[g]);
            acc[g] = fmaf(xv.y, w1, acc[g]);
            acc[g] = fmaf(xv.z, w2, acc[g]);
            acc[g] = fmaf(xv.w, w3, acc[g]);
        }
    }
    if (q == 3) {
        #pragma unroll
        for (int g = 0; g < 8; ++g) sS[g][c] = acc[g];
    }
    __syncthreads();
    #pragma unroll
    for (int g = 0; g < 8; ++g) {
        const size_t n = n0 + g;
        if (q == 0)      Pi[n * 128 + c]      = acc[g];
        else if (q == 2) Pi[n * 128 + 64 + c] = acc[g];
        else if (q == 1) Pj16[n * 64 + c]     = __floats2half2_rn(acc[g], sS[g][c]);
    }
}

// ---------------- edge-parallel row-range conv: 8 rows/block,
//    2 channels/lane, half-wave = edge, WAVE-UNIFORM control flow ----------------
__launch_bounds__(256, 7)
__global__ void k_edge_range(const __half2* __restrict__ Pj,
                             const float* __restrict__ Pi,
                             const int2* __restrict__ rcP, const float4* __restrict__ ewP,
                             const float* __restrict__ wfe, const float* __restrict__ wse,
                             const int* __restrict__ rs,
                             const float* __restrict__ xin, float* __restrict__ out) {
    __shared__ __align__(16) float piS[8][128];     // 4 KB
    __shared__ __align__(16) float accS[8][8][64];  // 16 KB: [half-wave][row][ch]
    __shared__ int rsS[9];
    const int tid = threadIdx.x;
    const int hw = tid >> 5;            // half-wave id 0..7
    const int hb = hw & 1;              // edge-within-pair bit
    const int wv = tid >> 6;            // wave 0..3
    const int c2 = (tid & 31) * 2;      // channel pair base
    const int r0 = blockIdx.x * 8;
    for (int i = tid; i < 1024; i += 256)
        piS[i >> 7][i & 127] = Pi[(size_t)r0 * 128 + i];
    for (int i = tid; i < 4096; i += 256)
        ((float*)accS)[i] = 0.f;
    if (tid < 9) rsS[tid] = rs[r0 + tid];
    __syncthreads();
    const float wf0a = wfe[c2],       wf0b = wfe[c2 + 1];
    const float wf1a = wfe[64 + c2],  wf1b = wfe[64 + c2 + 1];
    const float wf2a = wfe[128 + c2], wf2b = wfe[128 + c2 + 1];
    const float ws0a = wse[c2],       ws0b = wse[c2 + 1];
    const float ws1a = wse[64 + c2],  ws1b = wse[64 + c2 + 1];
    const float ws2a = wse[128 + c2], ws2b = wse[128 + c2 + 1];
    const int pbeg = rsS[0], pend = rsS[8];

#define EDGE_BODY(P)                                                              \
    {                                                                             \
        const int2 rc = rcP[P];                                                   \
        const float4 e = ewP[P];                                                  \
        const uint2 Jraw = *(const uint2*)&Pj[rc.y * 64 + c2];                    \
        const float2 Ja = __half22float2(*(const __half2*)&Jraw.x);               \
        const float2 Jb = __half22float2(*(const __half2*)&Jraw.y);               \
        const int row = rc.x - r0;                                                \
        const float2 pf = *(const float2*)&piS[row][c2];                          \
        const float2 ps = *(const float2*)&piS[row][64 + c2];                     \
        const float afa = pf.x + Ja.x + e.x * wf0a + e.y * wf1a + e.z * wf2a;     \
        const float asa = ps.x + Ja.y + e.x * ws0a + e.y * ws1a + e.z * ws2a;     \
        const float afb = pf.y + Jb.x + e.x * wf0b + e.y * wf1b + e.z * wf2b;     \
        const float asb = ps.y + Jb.y + e.x * ws0b + e.y * ws1b + e.z * ws2b;     \
        const float sga = 1.f / (1.f + __expf(-afa));                             \
        const float spa = (asa > 20.f) ? asa : __logf(1.f + __expf(asa));         \
        const float sgb = 1.f / (1.f + __expf(-afb));                             \
        const float spb = (asb > 20.f) ? asb : __logf(1.f + __expf(asb));         \
        float2 acc = *(const float2*)&accS[hw][row][c2];                          \
        acc.x = fmaf(sga, spa, acc.x);                                            \
        acc.y = fmaf(sgb, spb, acc.y);                                            \
        *(float2*)&accS[hw][row][c2] = acc;                                       \
    }

    // main loop: wave-uniform bounds (pair [p0, p0+1] both valid)
    int p0 = pbeg + 2 * wv;
    #pragma unroll 2
    for (; p0 + 2 <= pend; p0 += 8) {
        const int p = p0 + hb;
        EDGE_BODY(p)
    }
    // tail: at most one partial pair per wave (divergent guard, runs once)
    {
        const int p = p0 + hb;
        if (p < pend) EDGE_BODY(p)
    }
#undef EDGE_BODY

    __syncthreads();
    for (int i = tid; i < 512; i += 256) {
        const int row = i >> 6, ch = i & 63;
        float s = 0.f;
        #pragma unroll
        for (int a = 0; a < 8; ++a) s += accS[a][row][ch];
        const int deg = rsS[row + 1] - rsS[row];
        const size_t o = (size_t)(r0 + row) * 64 + ch;
        out[o] = fmaxf(fmaf(s, 1.f / (float)max(deg, 1), xin[o]), 0.f);
    }
}

// ---------------- fused GRU: h = GRU(m, h), weights from L2 ----------------
__global__ void k_gru_fused(const float* __restrict__ m, float* __restrict__ h,
                            const float* __restrict__ wih, const float* __restrict__ bih,
                            const float* __restrict__ whh, const float* __restrict__ bhh) {
    __shared__ __align__(16) float ms[32][64];
    __shared__ __align__(16) float hs[32][64];
    const int tid = threadIdx.x;
    const int n0 = blockIdx.x * 32;
    for (int i = tid; i < 2048; i += 256) {
        ms[i >> 6][i & 63] = m[(size_t)n0 * 64 + i];
        hs[i >> 6][i & 63] = h[(size_t)n0 * 64 + i];
    }
    __syncthreads();
    const int c = tid & 63, tg = tid >> 6;
    float ir[8], iz[8], inn[8], hr[8], hz[8], hn[8];
    #pragma unroll
    for (int j = 0; j < 8; ++j) { ir[j]=0.f; iz[j]=0.f; inn[j]=0.f; hr[j]=0.f; hz[j]=0.f; hn[j]=0.f; }
    for (int k4 = 0; k4 < 64; k4 += 4) {
        float wir[4], wiz[4], win[4], whr[4], whz[4], whn[4];
        #pragma unroll
        for (int u = 0; u < 4; ++u) {
            const int k = k4 + u;
            wir[u] = wih[k * 192 + c];
            wiz[u] = wih[k * 192 + 64 + c];
            win[u] = wih[k * 192 + 128 + c];
            whr[u] = whh[k * 192 + c];
            whz[u] = whh[k * 192 + 64 + c];
            whn[u] = whh[k * 192 + 128 + c];
        }
        #pragma unroll
        for (int j = 0; j < 8; ++j) {
            const int nrow = j * 4 + tg;
            const float4 mv = *(const float4*)&ms[nrow][k4];
            const float4 hv = *(const float4*)&hs[nrow][k4];
            ir[j]  = fmaf(mv.x, wir[0], ir[j]);  ir[j]  = fmaf(mv.y, wir[1], ir[j]);
            ir[j]  = fmaf(mv.z, wir[2], ir[j]);  ir[j]  = fmaf(mv.w, wir[3], ir[j]);
            iz[j]  = fmaf(mv.x, wiz[0], iz[j]);  iz[j]  = fmaf(mv.y, wiz[1], iz[j]);
            iz[j]  = fmaf(mv.z, wiz[2], iz[j]);  iz[j]  = fmaf(mv.w, wiz[3], iz[j]);
            inn[j] = fmaf(mv.x, win[0], inn[j]); inn[j] = fmaf(mv.y, win[1], inn[j]);
            inn[j] = fmaf(mv.z, win[2], inn[j]); inn[j] = fmaf(mv.w, win[3], inn[j]);
            hr[j]  = fmaf(hv.x, whr[0], hr[j]);  hr[j]  = fmaf(hv.y, whr[1], hr[j]);
            hr[j]  = fmaf(hv.z, whr[2], hr[j]);  hr[j]  = fmaf(hv.w, whr[3], hr[j]);
            hz[j]  = fmaf(hv.x, whz[0], hz[j]);  hz[j]  = fmaf(hv.y, whz[1], hz[j]);
            hz[j]  = fmaf(hv.z, whz[2], hz[j]);  hz[j]  = fmaf(hv.w, whz[3], hz[j]);
            hn[j]  = fmaf(hv.x, whn[0], hn[j]);  hn[j]  = fmaf(hv.y, whn[1], hn[j]);
            hn[j]  = fmaf(hv.z, whn[2], hn[j]);  hn[j]  = fmaf(hv.w, whn[3], hn[j]);
        }
    }
    const float bir = bih[c], biz = bih[64 + c], bin = bih[128 + c];
    const float bhr = bhh[c], bhz = bhh[64 + c], bhn = bhh[128 + c];
    #pragma unroll
    for (int j = 0; j < 8; ++j) {
        const int n = n0 + j * 4 + tg;
        const float r  = 1.f / (1.f + __expf(-((ir[j] + bir) + (hr[j] + bhr))));
        const float zg = 1.f / (1.f + __expf(-((iz[j] + biz) + (hz[j] + bhz))));
        const float ng = tanhf((inn[j] + bin) + r * (hn[j] + bhn));
        h[(size_t)n * 64 + c] = (1.f - zg) * ng + zg * hs[j * 4 + tg][c];
    }
}

// ---------------- first-node-per-graph indices (searchsorted) ----------------
__global__ void k_idx(const int* __restrict__ batch, int* __restrict__ idx) {
    int g = threadIdx.x;
    if (g >= NGRAPH) return;
    int lo = 0, hi = NN;
    while (lo < hi) {
        int mid = (lo + hi) >> 1;
        if (batch[mid] < g) lo = mid + 1; else hi = mid;
    }
    idx[g] = lo;
}

// ---------------- readout head: all weights/activations in LDS ----------------
__global__ void k_head(const float* __restrict__ h, const int* __restrict__ idx,
                       const float* __restrict__ fcsw, const float* __restrict__ fcsb,
                       const float* __restrict__ f2cw, const float* __restrict__ f2cb,
                       const float* __restrict__ f3cw, const float* __restrict__ f3cb,
                       const float* __restrict__ f2dw, const float* __restrict__ f2db,
                       const float* __restrict__ f3dw, const float* __restrict__ f3db,
                       float* __restrict__ out) {
    __shared__ float hsB[4096];
    __shared__ float waB[4096];
    __shared__ float wbB[4096];
    __shared__ float wcB[4096];
    const int tid = threadIdx.x;
    for (int i = tid; i < 4096; i += 256) {
        int g = i >> 6, k = i & 63;
        hsB[i] = h[(size_t)idx[g] * 64 + k];
        waB[i] = fcsw[i];
        wbB[i] = f2cw[i];
        wcB[i] = f2dw[i];
    }
    __syncthreads();
    float v[16];
    #pragma unroll
    for (int j = 0; j < 16; ++j) {
        const int i = j * 256 + tid, g = i >> 6, c = i & 63;
        float a = fcsb[c];
        for (int k = 0; k < 64; ++k) a = fmaf(hsB[g * 64 + k], waB[k * 64 + c], a);
        v[j] = fmaxf(a, 0.f);
    }
    __syncthreads();
    #pragma unroll
    for (int j = 0; j < 16; ++j) hsB[j * 256 + tid] = v[j];
    __syncthreads();
    float vc[16], vd[16];
    #pragma unroll
    for (int j = 0; j < 16; ++j) {
        const int i = j * 256 + tid, g = i >> 6, c = i & 63;
        float a1 = f2cb[c], a2 = f2db[c];
        for (int k = 0; k < 64; ++k) {
            const float xv = hsB[g * 64 + k];
            a1 = fmaf(xv, wbB[k * 64 + c], a1);
            a2 = fmaf(xv, wcB[k * 64 + c], a2);
        }
        vc[j] = fmaxf(a1, 0.f);
        vd[j] = fmaxf(a2, 0.f);
    }
    __syncthreads();
    #pragma unroll
    for (int j = 0; j < 16; ++j) {
        waB[j * 256 + tid] = vc[j];
        wbB[j * 256 + tid] = vd[j];
    }
    if (tid < 128) wcB[tid] = f3cw[tid];
    else           wcB[tid] = f3dw[tid - 128];
    __syncthreads();
    if (tid < 128) {
        int g = tid >> 1, j = tid & 1;
        float a = f3cb[j];
        for (int k = 0; k < 64; ++k) a = fmaf(waB[g * 64 + k], wcB[k * 2 + j], a);
        out[g * 2 + j] = 1.f / (1.f + expf(-a));
    } else {
        int t = tid - 128, g = t >> 1, j = t & 1;
        float a = f3db[j];
        for (int k = 0; k < 64; ++k) a = fmaf(wbB[g * 64 + k], wcB[128 + k * 2 + j], a);
        out[128 + g * 2 + j] = a;
    }
}

// ---------------- host launcher ----------------
extern "C" void kernel_launch(void* const* d_in, const int* in_sizes, int n_in,
                              void* d_out, int out_size, void* d_ws, size_t ws_size,
                              hipStream_t stream) {
    (void)in_sizes; (void)n_in; (void)out_size; (void)ws_size;
    const float* x    = (const float*)d_in[0];
    const int* ei1    = (const int*)d_in[1];
    const int* ei2    = (const int*)d_in[2];
    const float* w1   = (const float*)d_in[3];
    const float* w2   = (const float*)d_in[4];
    const int* batch  = (const int*)d_in[5];
    const float* fc1w = (const float*)d_in[6];
    const float* fc1b = (const float*)d_in[7];
    const float* lfw  = (const float*)d_in[8];
    const float* lfb  = (const float*)d_in[9];
    const float* lsw  = (const float*)d_in[10];
    const float* lsb  = (const float*)d_in[11];
    const float* wih  = (const float*)d_in[12];
    const float* bih  = (const float*)d_in[13];
    const float* whh  = (const float*)d_in[14];
    const float* bhh  = (const float*)d_in[15];
    const float* fcsw = (const float*)d_in[16];
    const float* fcsb = (const float*)d_in[17];
    const float* f2cw = (const float*)d_in[18];
    const float* f2cb = (const float*)d_in[19];
    const float* f3cw = (const float*)d_in[20];
    const float* f3cb = (const float*)d_in[21];
    const float* f2dw = (const float*)d_in[22];
    const float* f2db = (const float*)d_in[23];
    const float* f3dw = (const float*)d_in[24];
    const float* f3db = (const float*)d_in[25];

    char* ws = (char*)d_ws;
    size_t off = 0;
    auto alloc = [&](size_t bytes) { char* p = ws + off; off += (bytes + 255) & ~size_t(255); return p; };
    float*   Pi    = (float*)alloc(size_t(NN) * 128 * 4);      // 20.5 MB
    __half2* Pj16  = (__half2*)alloc(size_t(NN) * 64 * 4);     // 10.2 MB
    float*   hbuf  = (float*)alloc(size_t(NN) * CD * 4);
    float*   mbuf  = (float*)alloc(size_t(NN) * CD * 4);
    int*   cnt1  = (int*)alloc(size_t(NN) * 4);                // cnt1+cnt2 adjacent: one memset
    int*   cnt2  = (int*)alloc(size_t(NN) * 4);
    int*   rs1   = (int*)alloc(size_t(NN + 1) * 4);
    int*   rs2   = (int*)alloc(size_t(NN + 1) * 4);
    int*   cur1  = (int*)alloc(size_t(NN + 1) * 4);
    int*   cur2  = (int*)alloc(size_t(NN + 1) * 4);
    int*   perm1 = (int*)alloc(size_t(NE) * 4);
    int*   perm2 = (int*)alloc(size_t(NE) * 4);
    int2*  rcP1  = (int2*)alloc(size_t(NE) * 8);
    int2*  rcP2  = (int2*)alloc(size_t(NE) * 8);
    float4* ewP1 = (float4*)alloc(size_t(NE) * 16);
    float4* ewP2 = (float4*)alloc(size_t(NE) * 16);
    int*   part1 = (int*)alloc(256 * 4);
    int*   part2 = (int*)alloc(256 * 4);
    int*   offs1 = (int*)alloc(256 * 4);
    int*   offs2 = (int*)alloc(256 * 4);
    int*   idx   = (int*)alloc(256);

    const int NB_NC = (NN * CD + 255) / 256;
    const int EDGE_BLOCKS = NN / 8;    // 5000 row-range blocks
    const int PROJ_BLOCKS = NN / 8;    // 5000
    const int GRU_BLOCKS  = NN / 32;   // 1250

    const float* lfe = lfw + 128 * 64;
    const float* lse = lsw + 128 * 64;

    // CSR build: merged two-set kernels (7 dispatches total)
    hipMemsetAsync(cnt1, 0, size_t(NN) * 4 * 2 + 256, stream);   // covers cnt1+cnt2 (adjacent)
    k_count2<<<2 * EBLK, 256, 0, stream>>>(ei1, ei2, cnt1, cnt2);
    k_scan_part2<<<2 * SCAN_BLOCKS, 256, 0, stream>>>(cnt1, cnt2, part1, part2);
    k_scan_mid2<<<2, 256, 0, stream>>>(part1, part2, offs1, offs2);
    k_scan_fill2<<<2 * SCAN_BLOCKS, 256, 0, stream>>>(cnt1, cnt2, offs1, offs2, rs1, rs2, cur1, cur2);
    k_scatter2<<<2 * EBLK, 256, 0, stream>>>(ei1, ei2, cur1, cur2, perm1, perm2);
    k_edge_gather2<<<2 * EBLK, 256, 0, stream>>>(ei1, ei2, w1, w2, perm1, perm2,
                                                 rcP1, rcP2, ewP1, ewP2);

    k_fc1<<<NB_NC, 256, 0, stream>>>(x, fc1w, fc1b, hbuf);

    for (int it = 0; it < 3; ++it) {
        k_proj<<<PROJ_BLOCKS, 256, 0, stream>>>(hbuf, lfw, lfb, lsw, lsb, Pi, Pj16);
        k_edge_range<<<EDGE_BLOCKS, 256, 0, stream>>>(Pj16, Pi, rcP2, ewP2,
                                                      lfe, lse, rs2, hbuf, mbuf);
        k_proj<<<PROJ_BLOCKS, 256, 0, stream>>>(mbuf, lfw, lfb, lsw, lsb, Pi, Pj16);
        k_edge_range<<<EDGE_BLOCKS, 256, 0, stream>>>(Pj16, Pi, rcP1, ewP1,
                                                      lfe, lse, rs1, mbuf, mbuf);
        k_gru_fused<<<GRU_BLOCKS, 256, 0, stream>>>(mbuf, hbuf, wih, bih, whh, bhh);
    }

    k_idx<<<1, 64, 0, stream>>>(batch, idx);
    k_head<<<1, 256, 0, stream>>>(hbuf, idx, fcsw, fcsb, f2cw, f2cb, f3cw, f3cb,
                                  f2dw, f2db, f3dw, f3db, (float*)d_out);
}

// Round 18
// 660.468 us; speedup vs baseline: 1.1949x; 1.1028x over previous
//
#include <hip/hip_runtime.h>
#include <hip/hip_bf16.h>
#include <hip/hip_fp16.h>
#include <math.h>

constexpr int NE = 400000;
constexpr int NN = 40000;
constexpr int CD = 64;
constexpr int NGRAPH = 64;
constexpr int SCAN_BLOCKS = (NN + 255) / 256;   // 157
constexpr int EBLK = (NE + 255) / 256;          // 1563

typedef _Float16 f16x8 __attribute__((ext_vector_type(8)));
typedef float f32x4 __attribute__((ext_vector_type(4)));

// ---------------- fc1: x0 = relu(x @ fc1_w + b) ----------------
__global__ void k_fc1(const float* __restrict__ x,
                      const float* __restrict__ w,
                      const float* __restrict__ b,
                      float* __restrict__ out) {
    int i = blockIdx.x * 256 + threadIdx.x;
    if (i >= NN * CD) return;
    int n = i >> 6, c = i & 63;
    float acc = b[c];
    #pragma unroll
    for (int k = 0; k < 9; ++k)
        acc = fmaf(x[n * 9 + k], w[k * 64 + c], acc);
    out[i] = fmaxf(acc, 0.f);
}

// ---------------- edge counts, both sets ----------------
__global__ void k_count2(const int* __restrict__ ei1, const int* __restrict__ ei2,
                         int* __restrict__ cnt1, int* __restrict__ cnt2) {
    const int b = blockIdx.x;
    const bool s2 = (b >= EBLK);
    const int* ei = s2 ? ei2 : ei1;
    int* cnt = s2 ? cnt2 : cnt1;
    int e = (s2 ? b - EBLK : b) * 256 + threadIdx.x;
    if (e >= NE) return;
    atomicAdd(&cnt[ei[e]], 1);
}

// ---------------- parallel scan phase 1, both sets ----------------
__global__ void k_scan_part2(const int* __restrict__ cnt1, const int* __restrict__ cnt2,
                             int* __restrict__ part1, int* __restrict__ part2) {
    __shared__ int red[256];
    const int b = blockIdx.x;
    const bool s2 = (b >= SCAN_BLOCKS);
    const int* cnt = s2 ? cnt2 : cnt1;
    int* partials = s2 ? part2 : part1;
    const int bb = s2 ? b - SCAN_BLOCKS : b;
    const int tid = threadIdx.x;
    const int i = bb * 256 + tid;
    red[tid] = (i < NN) ? cnt[i] : 0;
    __syncthreads();
    for (int s = 128; s > 0; s >>= 1) {
        if (tid < s) red[tid] += red[tid + s];
        __syncthreads();
    }
    if (tid == 0) partials[bb] = red[0];
}

// ---------------- phase 2, both sets (2 blocks) ----------------
__global__ void k_scan_mid2(const int* __restrict__ part1, const int* __restrict__ part2,
                            int* __restrict__ offs1, int* __restrict__ offs2) {
    __shared__ int part[256];
    const bool s2 = (blockIdx.x == 1);
    const int* partials = s2 ? part2 : part1;
    int* offs = s2 ? offs2 : offs1;
    const int tid = threadIdx.x;
    const int v = (tid < SCAN_BLOCKS) ? partials[tid] : 0;
    part[tid] = v;
    __syncthreads();
    for (int off = 1; off < 256; off <<= 1) {
        int t = (tid >= off) ? part[tid - off] : 0;
        __syncthreads();
        part[tid] += t;
        __syncthreads();
    }
    if (tid < SCAN_BLOCKS) offs[tid] = part[tid] - v;
}

// ---------------- phase 3, both sets ----------------
__global__ void k_scan_fill2(const int* __restrict__ cnt1, const int* __restrict__ cnt2,
                             const int* __restrict__ offs1, const int* __restrict__ offs2,
                             int* __restrict__ rs1, int* __restrict__ rs2,
                             int* __restrict__ cur1, int* __restrict__ cur2) {
    __shared__ int part[256];
    const int b = blockIdx.x;
    const bool s2 = (b >= SCAN_BLOCKS);
    const int* cnt = s2 ? cnt2 : cnt1;
    const int* offs = s2 ? offs2 : offs1;
    int* row_start = s2 ? rs2 : rs1;
    int* cursor = s2 ? cur2 : cur1;
    const int bb = s2 ? b - SCAN_BLOCKS : b;
    const int tid = threadIdx.x;
    const int i = bb * 256 + tid;
    const int v = (i < NN) ? cnt[i] : 0;
    part[tid] = v;
    __syncthreads();
    for (int off = 1; off < 256; off <<= 1) {
        int t = (tid >= off) ? part[tid - off] : 0;
        __syncthreads();
        part[tid] += t;
        __syncthreads();
    }
    const int excl = part[tid] - v + offs[bb];
    if (i < NN) { row_start[i] = excl; cursor[i] = excl; }
    if (i == NN - 1) row_start[NN] = NE;
}

// ---------------- scatter, both sets ----------------
__global__ void k_scatter2(const int* __restrict__ ei1, const int* __restrict__ ei2,
                           int* __restrict__ cur1, int* __restrict__ cur2,
                           int* __restrict__ perm1, int* __restrict__ perm2) {
    const int b = blockIdx.x;
    const bool s2 = (b >= EBLK);
    const int* ei = s2 ? ei2 : ei1;
    int* cursor = s2 ? cur2 : cur1;
    int* perm = s2 ? perm2 : perm1;
    int e = (s2 ? b - EBLK : b) * 256 + threadIdx.x;
    if (e >= NE) return;
    int pos = atomicAdd(&cursor[ei[e]], 1);
    perm[pos] = e;
}

// ---------------- pre-gather packed edge data, both sets ----------------
__global__ void k_edge_gather2(const int* __restrict__ ei1, const int* __restrict__ ei2,
                               const float* __restrict__ w1, const float* __restrict__ w2,
                               const int* __restrict__ perm1, const int* __restrict__ perm2,
                               int2* __restrict__ rcP1, int2* __restrict__ rcP2,
                               float4* __restrict__ ewP1, float4* __restrict__ ewP2) {
    const int b = blockIdx.x;
    const bool s2 = (b >= EBLK);
    const int* ei = s2 ? ei2 : ei1;
    const float* ew = s2 ? w2 : w1;
    const int* perm = s2 ? perm2 : perm1;
    int2* rcP = s2 ? rcP2 : rcP1;
    float4* ewP = s2 ? ewP2 : ewP1;
    int p = (s2 ? b - EBLK : b) * 256 + threadIdx.x;
    if (p >= NE) return;
    const int e = perm[p];
    rcP[p] = make_int2(ei[e], ei[NE + e]);
    ewP[p] = make_float4(ew[3 * e], ew[3 * e + 1], ew[3 * e + 2], 0.f);
}

// ---------------- one-time: Wt[c][k] = f16(W_big[k][c]) ----------------
// W_big cols: 0..63 lfw_top, 64..127 lsw_top, 128..191 lfw_bot, 192..255 lsw_bot
__global__ void k_wt16(const float* __restrict__ lfw, const float* __restrict__ lsw,
                       _Float16* __restrict__ Wt) {
    const int k = blockIdx.x;       // 0..63
    const int c = threadIdx.x;      // 0..255
    float v;
    if (c < 64)       v = lfw[k * 64 + c];
    else if (c < 128) v = lsw[k * 64 + (c - 64)];
    else if (c < 192) v = lfw[(64 + k) * 64 + (c - 128)];
    else              v = lsw[(64 + k) * 64 + (c - 192)];
    Wt[c * 64 + k] = (_Float16)v;
}

// ---------------- MFMA node projection: P = X @ W_big (f16 in, f32 acc) ----------------
// Pi[n][0:64]=bf+f_top, [64:128]=bs+s_top; Pj16[n][c]=half2(f_bot, s_bot)
__launch_bounds__(256, 4)
__global__ void k_proj_mfma(const float* __restrict__ x,
                            const _Float16* __restrict__ Wt,
                            const float* __restrict__ bfp, const float* __restrict__ bsp,
                            float* __restrict__ Pi, __half2* __restrict__ Pj16) {
    __shared__ _Float16 xs16[32][72];   // pad 72: 2-way bank alias on b128 reads
    const int tid = threadIdx.x;
    const int n0 = blockIdx.x * 32;
    {
        const int n = tid >> 3, k0 = (tid & 7) * 8;
        const float4 a = *(const float4*)&x[(size_t)(n0 + n) * 64 + k0];
        const float4 b = *(const float4*)&x[(size_t)(n0 + n) * 64 + k0 + 4];
        f16x8 v;
        v[0] = (_Float16)a.x; v[1] = (_Float16)a.y; v[2] = (_Float16)a.z; v[3] = (_Float16)a.w;
        v[4] = (_Float16)b.x; v[5] = (_Float16)b.y; v[6] = (_Float16)b.z; v[7] = (_Float16)b.w;
        *(f16x8*)&xs16[n][k0] = v;
    }
    __syncthreads();
    const int l  = tid & 63;
    const int w  = tid >> 6;
    const int lr = l & 15;              // in-tile row/col index
    const int kb = l >> 4;              // k-block (A/B) / row-block (D)
    const int nt = w & 1;               // node-tile 0/1
    // A-frags: A[lr][kb*8+j] for K-halves 0 and 1
    const f16x8 A0 = *(const f16x8*)&xs16[nt * 16 + lr][kb * 8];
    const f16x8 A1 = *(const f16x8*)&xs16[nt * 16 + lr][32 + kb * 8];
    const int orow = n0 + nt * 16 + kb * 4;   // D rows orow..orow+3 (reg r)

    if (w < 2) {
        // Pi col-tiles 0..7 (W cols 0..127)
        for (int ct = 0; ct < 8; ++ct) {
            const int col = ct * 16 + lr;
            const f16x8 B0 = *(const f16x8*)&Wt[col * 64 + kb * 8];
            const f16x8 B1 = *(const f16x8*)&Wt[col * 64 + 32 + kb * 8];
            f32x4 acc = {0.f, 0.f, 0.f, 0.f};
            acc = __builtin_amdgcn_mfma_f32_16x16x32_f16(A0, B0, acc, 0, 0, 0);
            acc = __builtin_amdgcn_mfma_f32_16x16x32_f16(A1, B1, acc, 0, 0, 0);
            const float bias = (col < 64) ? bfp[col] : bsp[col - 64];
            #pragma unroll
            for (int r = 0; r < 4; ++r)
                Pi[(size_t)(orow + r) * 128 + col] = acc[r] + bias;
        }
    } else {
        // Pj pairs pt 0..3: F = W cols 128+pt*16.., S = W cols 192+pt*16..
        for (int pt = 0; pt < 4; ++pt) {
            const int colF = 128 + pt * 16 + lr;
            const int colS = 192 + pt * 16 + lr;
            const f16x8 BF0 = *(const f16x8*)&Wt[colF * 64 + kb * 8];
            const f16x8 BF1 = *(const f16x8*)&Wt[colF * 64 + 32 + kb * 8];
            const f16x8 BS0 = *(const f16x8*)&Wt[colS * 64 + kb * 8];
            const f16x8 BS1 = *(const f16x8*)&Wt[colS * 64 + 32 + kb * 8];
            f32x4 aF = {0.f, 0.f, 0.f, 0.f}, aS = {0.f, 0.f, 0.f, 0.f};
            aF = __builtin_amdgcn_mfma_f32_16x16x32_f16(A0, BF0, aF, 0, 0, 0);
            aF = __builtin_amdgcn_mfma_f32_16x16x32_f16(A1, BF1, aF, 0, 0, 0);
            aS = __builtin_amdgcn_mfma_f32_16x16x32_f16(A0, BS0, aS, 0, 0, 0);
            aS = __builtin_amdgcn_mfma_f32_16x16x32_f16(A1, BS1, aS, 0, 0, 0);
            const int cj = pt * 16 + lr;
            #pragma unroll
            for (int r = 0; r < 4; ++r)
                Pj16[(size_t)(orow + r) * 64 + cj] = __floats2half2_rn((float)aF[r], (float)aS[r]);
        }
    }
}

// ---------------- edge-parallel row-range conv (round-17 form, unchanged) ----------------
__launch_bounds__(256, 7)
__global__ void k_edge_range(const __half2* __restrict__ Pj,
                             const float* __restrict__ Pi,
                             const int2* __restrict__ rcP, const float4* __restrict__ ewP,
                             const float* __restrict__ wfe, const float* __restrict__ wse,
                             const int* __restrict__ rs,
                             const float* __restrict__ xin, float* __restrict__ out) {
    __shared__ __align__(16) float piS[8][128];
    __shared__ __align__(16) float accS[8][8][64];
    __shared__ int rsS[9];
    const int tid = threadIdx.x;
    const int hw = tid >> 5;
    const int hb = hw & 1;
    const int wv = tid >> 6;
    const int c2 = (tid & 31) * 2;
    const int r0 = blockIdx.x * 8;
    for (int i = tid; i < 1024; i += 256)
        piS[i >> 7][i & 127] = Pi[(size_t)r0 * 128 + i];
    for (int i = tid; i < 4096; i += 256)
        ((float*)accS)[i] = 0.f;
    if (tid < 9) rsS[tid] = rs[r0 + tid];
    __syncthreads();
    const float wf0a = wfe[c2],       wf0b = wfe[c2 + 1];
    const float wf1a = wfe[64 + c2],  wf1b = wfe[64 + c2 + 1];
    const float wf2a = wfe[128 + c2], wf2b = wfe[128 + c2 + 1];
    const float ws0a = wse[c2],       ws0b = wse[c2 + 1];
    const float ws1a = wse[64 + c2],  ws1b = wse[64 + c2 + 1];
    const float ws2a = wse[128 + c2], ws2b = wse[128 + c2 + 1];
    const int pbeg = rsS[0], pend = rsS[8];

#define EDGE_BODY(P)                                                              \
    {                                                                             \
        const int2 rc = rcP[P];                                                   \
        const float4 e = ewP[P];                                                  \
        const uint2 Jraw = *(const uint2*)&Pj[rc.y * 64 + c2];                    \
        const float2 Ja = __half22float2(*(const __half2*)&Jraw.x);               \
        const float2 Jb = __half22float2(*(const __half2*)&Jraw.y);               \
        const int row = rc.x - r0;                                                \
        const float2 pf = *(const float2*)&piS[row][c2];                          \
        const float2 ps = *(const float2*)&piS[row][64 + c2];                     \
        const float afa = pf.x + Ja.x + e.x * wf0a + e.y * wf1a + e.z * wf2a;     \
        const float asa = ps.x + Ja.y + e.x * ws0a + e.y * ws1a + e.z * ws2a;     \
        const float afb = pf.y + Jb.x + e.x * wf0b + e.y * wf1b + e.z * wf2b;     \
        const float asb = ps.y + Jb.y + e.x * ws0b + e.y * ws1b + e.z * ws2b;     \
        const float sga = 1.f / (1.f + __expf(-afa));                             \
        const float spa = (asa > 20.f) ? asa : __logf(1.f + __expf(asa));         \
        const float sgb = 1.f / (1.f + __expf(-afb));                             \
        const float spb = (asb > 20.f) ? asb : __logf(1.f + __expf(asb));         \
        float2 acc = *(const float2*)&accS[hw][row][c2];                          \
        acc.x = fmaf(sga, spa, acc.x);                                            \
        acc.y = fmaf(sgb, spb, acc.y);                                            \
        *(float2*)&accS[hw][row][c2] = acc;                                       \
    }

    int p0 = pbeg + 2 * wv;
    #pragma unroll 2
    for (; p0 + 2 <= pend; p0 += 8) {
        const int p = p0 + hb;
        EDGE_BODY(p)
    }
    {
        const int p = p0 + hb;
        if (p < pend) EDGE_BODY(p)
    }
#undef EDGE_BODY

    __syncthreads();
    for (int i = tid; i < 512; i += 256) {
        const int row = i >> 6, ch = i & 63;
        float s = 0.f;
        #pragma unroll
        for (int a = 0; a < 8; ++a) s += accS[a][row][ch];
        const int deg = rsS[row + 1] - rsS[row];
        const size_t o = (size_t)(r0 + row) * 64 + ch;
        out[o] = fmaxf(fmaf(s, 1.f / (float)max(deg, 1), xin[o]), 0.f);
    }
}

// ---------------- fused GRU: h = GRU(m, h), weights from L2 ----------------
__global__ void k_gru_fused(const float* __restrict__ m, float* __restrict__ h,
                            const float* __restrict__ wih, const float* __restrict__ bih,
                            const float* __restrict__ whh, const float* __restrict__ bhh) {
    __shared__ __align__(16) float ms[32][64];
    __shared__ __align__(16) float hs[32][64];
    const int tid = threadIdx.x;
    const int n0 = blockIdx.x * 32;
    for (int i = tid; i < 2048; i += 256) {
        ms[i >> 6][i & 63] = m[(size_t)n0 * 64 + i];
        hs[i >> 6][i & 63] = h[(size_t)n0 * 64 + i];
    }
    __syncthreads();
    const int c = tid & 63, tg = tid >> 6;
    float ir[8], iz[8], inn[8], hr[8], hz[8], hn[8];
    #pragma unroll
    for (int j = 0; j < 8; ++j) { ir[j]=0.f; iz[j]=0.f; inn[j]=0.f; hr[j]=0.f; hz[j]=0.f; hn[j]=0.f; }
    for (int k4 = 0; k4 < 64; k4 += 4) {
        float wir[4], wiz[4], win[4], whr[4], whz[4], whn[4];
        #pragma unroll
        for (int u = 0; u < 4; ++u) {
            const int k = k4 + u;
            wir[u] = wih[k * 192 + c];
            wiz[u] = wih[k * 192 + 64 + c];
            win[u] = wih[k * 192 + 128 + c];
            whr[u] = whh[k * 192 + c];
            whz[u] = whh[k * 192 + 64 + c];
            whn[u] = whh[k * 192 + 128 + c];
        }
        #pragma unroll
        for (int j = 0; j < 8; ++j) {
            const int nrow = j * 4 + tg;
            const float4 mv = *(const float4*)&ms[nrow][k4];
            const float4 hv = *(const float4*)&hs[nrow][k4];
            ir[j]  = fmaf(mv.x, wir[0], ir[j]);  ir[j]  = fmaf(mv.y, wir[1], ir[j]);
            ir[j]  = fmaf(mv.z, wir[2], ir[j]);  ir[j]  = fmaf(mv.w, wir[3], ir[j]);
            iz[j]  = fmaf(mv.x, wiz[0], iz[j]);  iz[j]  = fmaf(mv.y, wiz[1], iz[j]);
            iz[j]  = fmaf(mv.z, wiz[2], iz[j]);  iz[j]  = fmaf(mv.w, wiz[3], iz[j]);
            inn[j] = fmaf(mv.x, win[0], inn[j]); inn[j] = fmaf(mv.y, win[1], inn[j]);
            inn[j] = fmaf(mv.z, win[2], inn[j]); inn[j] = fmaf(mv.w, win[3], inn[j]);
            hr[j]  = fmaf(hv.x, whr[0], hr[j]);  hr[j]  = fmaf(hv.y, whr[1], hr[j]);
            hr[j]  = fmaf(hv.z, whr[2], hr[j]);  hr[j]  = fmaf(hv.w, whr[3], hr[j]);
            hz[j]  = fmaf(hv.x, whz[0], hz[j]);  hz[j]  = fmaf(hv.y, whz[1], hz[j]);
            hz[j]  = fmaf(hv.z, whz[2], hz[j]);  hz[j]  = fmaf(hv.w, whz[3], hz[j]);
            hn[j]  = fmaf(hv.x, whn[0], hn[j]);  hn[j]  = fmaf(hv.y, whn[1], hn[j]);
            hn[j]  = fmaf(hv.z, whn[2], hn[j]);  hn[j]  = fmaf(hv.w, whn[3], hn[j]);
        }
    }
    const float bir = bih[c], biz = bih[64 + c], bin = bih[128 + c];
    const float bhr = bhh[c], bhz = bhh[64 + c], bhn = bhh[128 + c];
    #pragma unroll
    for (int j = 0; j < 8; ++j) {
        const int n = n0 + j * 4 + tg;
        const float r  = 1.f / (1.f + __expf(-((ir[j] + bir) + (hr[j] + bhr))));
        const float zg = 1.f / (1.f + __expf(-((iz[j] + biz) + (hz[j] + bhz))));
        const float ng = tanhf((inn[j] + bin) + r * (hn[j] + bhn));
        h[(size_t)n * 64 + c] = (1.f - zg) * ng + zg * hs[j * 4 + tg][c];
    }
}

// ---------------- first-node-per-graph indices (searchsorted) ----------------
__global__ void k_idx(const int* __restrict__ batch, int* __restrict__ idx) {
    int g = threadIdx.x;
    if (g >= NGRAPH) return;
    int lo = 0, hi = NN;
    while (lo < hi) {
        int mid = (lo + hi) >> 1;
        if (batch[mid] < g) lo = mid + 1; else hi = mid;
    }
    idx[g] = lo;
}

// ---------------- readout head: all weights/activations in LDS ----------------
__global__ void k_head(const float* __restrict__ h, const int* __restrict__ idx,
                       const float* __restrict__ fcsw, const float* __restrict__ fcsb,
                       const float* __restrict__ f2cw, const float* __restrict__ f2cb,
                       const float* __restrict__ f3cw, const float* __restrict__ f3cb,
                       const float* __restrict__ f2dw, const float* __restrict__ f2db,
                       const float* __restrict__ f3dw, const float* __restrict__ f3db,
                       float* __restrict__ out) {
    __shared__ float hsB[4096];
    __shared__ float waB[4096];
    __shared__ float wbB[4096];
    __shared__ float wcB[4096];
    const int tid = threadIdx.x;
    for (int i = tid; i < 4096; i += 256) {
        int g = i >> 6, k = i & 63;
        hsB[i] = h[(size_t)idx[g] * 64 + k];
        waB[i] = fcsw[i];
        wbB[i] = f2cw[i];
        wcB[i] = f2dw[i];
    }
    __syncthreads();
    float v[16];
    #pragma unroll
    for (int j = 0; j < 16; ++j) {
        const int i = j * 256 + tid, g = i >> 6, c = i & 63;
        float a = fcsb[c];
        for (int k = 0; k < 64; ++k) a = fmaf(hsB[g * 64 + k], waB[k * 64 + c], a);
        v[j] = fmaxf(a, 0.f);
    }
    __syncthreads();
    #pragma unroll
    for (int j = 0; j < 16; ++j) hsB[j * 256 + tid] = v[j];
    __syncthreads();
    float vc[16], vd[16];
    #pragma unroll
    for (int j = 0; j < 16; ++j) {
        const int i = j * 256 + tid, g = i >> 6, c = i & 63;
        float a1 = f2cb[c], a2 = f2db[c];
        for (int k = 0; k < 64; ++k) {
            const float xv = hsB[g * 64 + k];
            a1 = fmaf(xv, wbB[k * 64 + c], a1);
            a2 = fmaf(xv, wcB[k * 64 + c], a2);
        }
        vc[j] = fmaxf(a1, 0.f);
        vd[j] = fmaxf(a2, 0.f);
    }
    __syncthreads();
    #pragma unroll
    for (int j = 0; j < 16; ++j) {
        waB[j * 256 + tid] = vc[j];
        wbB[j * 256 + tid] = vd[j];
    }
    if (tid < 128) wcB[tid] = f3cw[tid];
    else           wcB[tid] = f3dw[tid - 128];
    __syncthreads();
    if (tid < 128) {
        int g = tid >> 1, j = tid & 1;
        float a = f3cb[j];
        for (int k = 0; k < 64; ++k) a = fmaf(waB[g * 64 + k], wcB[k * 2 + j], a);
        out[g * 2 + j] = 1.f / (1.f + expf(-a));
    } else {
        int t = tid - 128, g = t >> 1, j = t & 1;
        float a = f3db[j];
        for (int k = 0; k < 64; ++k) a = fmaf(wbB[g * 64 + k], wcB[128 + k * 2 + j], a);
        out[128 + g * 2 + j] = a;
    }
}

// ---------------- host launcher ----------------
extern "C" void kernel_launch(void* const* d_in, const int* in_sizes, int n_in,
                              void* d_out, int out_size, void* d_ws, size_t ws_size,
                              hipStream_t stream) {
    (void)in_sizes; (void)n_in; (void)out_size; (void)ws_size;
    const float* x    = (const float*)d_in[0];
    const int* ei1    = (const int*)d_in[1];
    const int* ei2    = (const int*)d_in[2];
    const float* w1   = (const float*)d_in[3];
    const float* w2   = (const float*)d_in[4];
    const int* batch  = (const int*)d_in[5];
    const float* fc1w = (const float*)d_in[6];
    const float* fc1b = (const float*)d_in[7];
    const float* lfw  = (const float*)d_in[8];
    const float* lfb  = (const float*)d_in[9];
    const float* lsw  = (const float*)d_in[10];
    const float* lsb  = (const float*)d_in[11];
    const float* wih  = (const float*)d_in[12];
    const float* bih  = (const float*)d_in[13];
    const float* whh  = (const float*)d_in[14];
    const float* bhh  = (const float*)d_in[15];
    const float* fcsw = (const float*)d_in[16];
    const float* fcsb = (const float*)d_in[17];
    const float* f2cw = (const float*)d_in[18];
    const float* f2cb = (const float*)d_in[19];
    const float* f3cw = (const float*)d_in[20];
    const float* f3cb = (const float*)d_in[21];
    const float* f2dw = (const float*)d_in[22];
    const float* f2db = (const float*)d_in[23];
    const float* f3dw = (const float*)d_in[24];
    const float* f3db = (const float*)d_in[25];

    char* ws = (char*)d_ws;
    size_t off = 0;
    auto alloc = [&](size_t bytes) { char* p = ws + off; off += (bytes + 255) & ~size_t(255); return p; };
    float*   Pi    = (float*)alloc(size_t(NN) * 128 * 4);      // 20.5 MB
    __half2* Pj16  = (__half2*)alloc(size_t(NN) * 64 * 4);     // 10.2 MB
    float*   hbuf  = (float*)alloc(size_t(NN) * CD * 4);
    float*   mbuf  = (float*)alloc(size_t(NN) * CD * 4);
    _Float16* W16  = (_Float16*)alloc(256 * 64 * 2);           // 32 KB, built once
    int*   cnt1  = (int*)alloc(size_t(NN) * 4);                // cnt1+cnt2 adjacent: one memset
    int*   cnt2  = (int*)alloc(size_t(NN) * 4);
    int*   rs1   = (int*)alloc(size_t(NN + 1) * 4);
    int*   rs2   = (int*)alloc(size_t(NN + 1) * 4);
    int*   cur1  = (int*)alloc(size_t(NN + 1) * 4);
    int*   cur2  = (int*)alloc(size_t(NN + 1) * 4);
    int*   perm1 = (int*)alloc(size_t(NE) * 4);
    int*   perm2 = (int*)alloc(size_t(NE) * 4);
    int2*  rcP1  = (int2*)alloc(size_t(NE) * 8);
    int2*  rcP2  = (int2*)alloc(size_t(NE) * 8);
    float4* ewP1 = (float4*)alloc(size_t(NE) * 16);
    float4* ewP2 = (float4*)alloc(size_t(NE) * 16);
    int*   part1 = (int*)alloc(256 * 4);
    int*   part2 = (int*)alloc(256 * 4);
    int*   offs1 = (int*)alloc(256 * 4);
    int*   offs2 = (int*)alloc(256 * 4);
    int*   idx   = (int*)alloc(256);

    const int NB_NC = (NN * CD + 255) / 256;
    const int EDGE_BLOCKS = NN / 8;     // 5000 row-range blocks
    const int PROJ_BLOCKS = NN / 32;    // 1250 MFMA blocks
    const int GRU_BLOCKS  = NN / 32;    // 1250

    const float* lfe = lfw + 128 * 64;
    const float* lse = lsw + 128 * 64;

    // CSR build + one-time f16 weight transpose
    hipMemsetAsync(cnt1, 0, size_t(NN) * 4 * 2 + 256, stream);
    k_count2<<<2 * EBLK, 256, 0, stream>>>(ei1, ei2, cnt1, cnt2);
    k_scan_part2<<<2 * SCAN_BLOCKS, 256, 0, stream>>>(cnt1, cnt2, part1, part2);
    k_scan_mid2<<<2, 256, 0, stream>>>(part1, part2, offs1, offs2);
    k_scan_fill2<<<2 * SCAN_BLOCKS, 256, 0, stream>>>(cnt1, cnt2, offs1, offs2, rs1, rs2, cur1, cur2);
    k_scatter2<<<2 * EBLK, 256, 0, stream>>>(ei1, ei2, cur1, cur2, perm1, perm2);
    k_edge_gather2<<<2 * EBLK, 256, 0, stream>>>(ei1, ei2, w1, w2, perm1, perm2,
                                                 rcP1, rcP2, ewP1, ewP2);
    k_wt16<<<64, 256, 0, stream>>>(lfw, lsw, W16);

    k_fc1<<<NB_NC, 256, 0, stream>>>(x, fc1w, fc1b, hbuf);

    for (int it = 0; it < 3; ++it) {
        k_proj_mfma<<<PROJ_BLOCKS, 256, 0, stream>>>(hbuf, W16, lfb, lsb, Pi, Pj16);
        k_edge_range<<<EDGE_BLOCKS, 256, 0, stream>>>(Pj16, Pi, rcP2, ewP2,
                                                      lfe, lse, rs2, hbuf, mbuf);
        k_proj_mfma<<<PROJ_BLOCKS, 256, 0, stream>>>(mbuf, W16, lfb, lsb, Pi, Pj16);
        k_edge_range<<<EDGE_BLOCKS, 256, 0, stream>>>(Pj16, Pi, rcP1, ewP1,
                                                      lfe, lse, rs1, mbuf, mbuf);
        k_gru_fused<<<GRU_BLOCKS, 256, 0, stream>>>(mbuf, hbuf, wih, bih, whh, bhh);
    }

    k_idx<<<1, 64, 0, stream>>>(batch, idx);
    k_head<<<1, 256, 0, stream>>>(hbuf, idx, fcsw, fcsb, f2cw, f2cb, f3cw, f3cb,
                                  f2dw, f2db, f3dw, f3db, (float*)d_out);
}

// Round 19
// 590.631 us; speedup vs baseline: 1.3362x; 1.1182x over previous
//
#include <hip/hip_runtime.h>
#include <hip/hip_bf16.h>
#include <hip/hip_fp16.h>
#include <math.h>

constexpr int NE = 400000;
constexpr int NN = 40000;
constexpr int CD = 64;
constexpr int NGRAPH = 64;
constexpr int SCAN_BLOCKS = (NN + 255) / 256;   // 157
constexpr int EBLK = (NE + 255) / 256;          // 1563

typedef _Float16 f16x8 __attribute__((ext_vector_type(8)));
typedef float f32x4 __attribute__((ext_vector_type(4)));

// ---------------- fc1: x0 = relu(x @ fc1_w + b) ----------------
__global__ void k_fc1(const float* __restrict__ x,
                      const float* __restrict__ w,
                      const float* __restrict__ b,
                      float* __restrict__ out) {
    int i = blockIdx.x * 256 + threadIdx.x;
    if (i >= NN * CD) return;
    int n = i >> 6, c = i & 63;
    float acc = b[c];
    #pragma unroll
    for (int k = 0; k < 9; ++k)
        acc = fmaf(x[n * 9 + k], w[k * 64 + c], acc);
    out[i] = fmaxf(acc, 0.f);
}

// ---------------- edge counts, both sets ----------------
__global__ void k_count2(const int* __restrict__ ei1, const int* __restrict__ ei2,
                         int* __restrict__ cnt1, int* __restrict__ cnt2) {
    const int b = blockIdx.x;
    const bool s2 = (b >= EBLK);
    const int* ei = s2 ? ei2 : ei1;
    int* cnt = s2 ? cnt2 : cnt1;
    int e = (s2 ? b - EBLK : b) * 256 + threadIdx.x;
    if (e >= NE) return;
    atomicAdd(&cnt[ei[e]], 1);
}

// ---------------- parallel scan phase 1, both sets ----------------
__global__ void k_scan_part2(const int* __restrict__ cnt1, const int* __restrict__ cnt2,
                             int* __restrict__ part1, int* __restrict__ part2) {
    __shared__ int red[256];
    const int b = blockIdx.x;
    const bool s2 = (b >= SCAN_BLOCKS);
    const int* cnt = s2 ? cnt2 : cnt1;
    int* partials = s2 ? part2 : part1;
    const int bb = s2 ? b - SCAN_BLOCKS : b;
    const int tid = threadIdx.x;
    const int i = bb * 256 + tid;
    red[tid] = (i < NN) ? cnt[i] : 0;
    __syncthreads();
    for (int s = 128; s > 0; s >>= 1) {
        if (tid < s) red[tid] += red[tid + s];
        __syncthreads();
    }
    if (tid == 0) partials[bb] = red[0];
}

// ---------------- phase 2, both sets (2 blocks) ----------------
__global__ void k_scan_mid2(const int* __restrict__ part1, const int* __restrict__ part2,
                            int* __restrict__ offs1, int* __restrict__ offs2) {
    __shared__ int part[256];
    const bool s2 = (blockIdx.x == 1);
    const int* partials = s2 ? part2 : part1;
    int* offs = s2 ? offs2 : offs1;
    const int tid = threadIdx.x;
    const int v = (tid < SCAN_BLOCKS) ? partials[tid] : 0;
    part[tid] = v;
    __syncthreads();
    for (int off = 1; off < 256; off <<= 1) {
        int t = (tid >= off) ? part[tid - off] : 0;
        __syncthreads();
        part[tid] += t;
        __syncthreads();
    }
    if (tid < SCAN_BLOCKS) offs[tid] = part[tid] - v;
}

// ---------------- phase 3, both sets ----------------
__global__ void k_scan_fill2(const int* __restrict__ cnt1, const int* __restrict__ cnt2,
                             const int* __restrict__ offs1, const int* __restrict__ offs2,
                             int* __restrict__ rs1, int* __restrict__ rs2,
                             int* __restrict__ cur1, int* __restrict__ cur2) {
    __shared__ int part[256];
    const int b = blockIdx.x;
    const bool s2 = (b >= SCAN_BLOCKS);
    const int* cnt = s2 ? cnt2 : cnt1;
    const int* offs = s2 ? offs2 : offs1;
    int* row_start = s2 ? rs2 : rs1;
    int* cursor = s2 ? cur2 : cur1;
    const int bb = s2 ? b - SCAN_BLOCKS : b;
    const int tid = threadIdx.x;
    const int i = bb * 256 + tid;
    const int v = (i < NN) ? cnt[i] : 0;
    part[tid] = v;
    __syncthreads();
    for (int off = 1; off < 256; off <<= 1) {
        int t = (tid >= off) ? part[tid - off] : 0;
        __syncthreads();
        part[tid] += t;
        __syncthreads();
    }
    const int excl = part[tid] - v + offs[bb];
    if (i < NN) { row_start[i] = excl; cursor[i] = excl; }
    if (i == NN - 1) row_start[NN] = NE;
}

// ---------------- scatter, both sets ----------------
__global__ void k_scatter2(const int* __restrict__ ei1, const int* __restrict__ ei2,
                           int* __restrict__ cur1, int* __restrict__ cur2,
                           int* __restrict__ perm1, int* __restrict__ perm2) {
    const int b = blockIdx.x;
    const bool s2 = (b >= EBLK);
    const int* ei = s2 ? ei2 : ei1;
    int* cursor = s2 ? cur2 : cur1;
    int* perm = s2 ? perm2 : perm1;
    int e = (s2 ? b - EBLK : b) * 256 + threadIdx.x;
    if (e >= NE) return;
    int pos = atomicAdd(&cursor[ei[e]], 1);
    perm[pos] = e;
}

// ---------------- pre-gather packed edge data, both sets ----------------
__global__ void k_edge_gather2(const int* __restrict__ ei1, const int* __restrict__ ei2,
                               const float* __restrict__ w1, const float* __restrict__ w2,
                               const int* __restrict__ perm1, const int* __restrict__ perm2,
                               int2* __restrict__ rcP1, int2* __restrict__ rcP2,
                               float4* __restrict__ ewP1, float4* __restrict__ ewP2) {
    const int b = blockIdx.x;
    const bool s2 = (b >= EBLK);
    const int* ei = s2 ? ei2 : ei1;
    const float* ew = s2 ? w2 : w1;
    const int* perm = s2 ? perm2 : perm1;
    int2* rcP = s2 ? rcP2 : rcP1;
    float4* ewP = s2 ? ewP2 : ewP1;
    int p = (s2 ? b - EBLK : b) * 256 + threadIdx.x;
    if (p >= NE) return;
    const int e = perm[p];
    rcP[p] = make_int2(ei[e], ei[NE + e]);
    ewP[p] = make_float4(ew[3 * e], ew[3 * e + 1], ew[3 * e + 2], 0.f);
}

// ---------------- one-time: Wt[c][k] = f16(W_big[k][c]) (CGConv weights) ----------------
__global__ void k_wt16(const float* __restrict__ lfw, const float* __restrict__ lsw,
                       _Float16* __restrict__ Wt) {
    const int k = blockIdx.x;       // 0..63
    const int c = threadIdx.x;      // 0..255
    float v;
    if (c < 64)       v = lfw[k * 64 + c];
    else if (c < 128) v = lsw[k * 64 + (c - 64)];
    else if (c < 192) v = lfw[(64 + k) * 64 + (c - 128)];
    else              v = lsw[(64 + k) * 64 + (c - 192)];
    Wt[c * 64 + k] = (_Float16)v;
}

// ---------------- one-time: WtG[c][k] f16 — GRU weights (0..191 wih, 192..383 whh) ----------------
__global__ void k_wtg16(const float* __restrict__ wih, const float* __restrict__ whh,
                        _Float16* __restrict__ WtG) {
    const int i = blockIdx.x * 256 + threadIdx.x;   // 0..24575
    const int c = i >> 6, k = i & 63;
    const float v = (c < 192) ? wih[k * 192 + c] : whh[k * 192 + (c - 192)];
    WtG[c * 64 + k] = (_Float16)v;
}

// ---------------- MFMA node projection: P = X @ W_big (f16 in, f32 acc) ----------------
__launch_bounds__(256, 4)
__global__ void k_proj_mfma(const float* __restrict__ x,
                            const _Float16* __restrict__ Wt,
                            const float* __restrict__ bfp, const float* __restrict__ bsp,
                            float* __restrict__ Pi, __half2* __restrict__ Pj16) {
    __shared__ _Float16 xs16[32][72];
    const int tid = threadIdx.x;
    const int n0 = blockIdx.x * 32;
    {
        const int n = tid >> 3, k0 = (tid & 7) * 8;
        const float4 a = *(const float4*)&x[(size_t)(n0 + n) * 64 + k0];
        const float4 b = *(const float4*)&x[(size_t)(n0 + n) * 64 + k0 + 4];
        f16x8 v;
        v[0] = (_Float16)a.x; v[1] = (_Float16)a.y; v[2] = (_Float16)a.z; v[3] = (_Float16)a.w;
        v[4] = (_Float16)b.x; v[5] = (_Float16)b.y; v[6] = (_Float16)b.z; v[7] = (_Float16)b.w;
        *(f16x8*)&xs16[n][k0] = v;
    }
    __syncthreads();
    const int l  = tid & 63;
    const int w  = tid >> 6;
    const int lr = l & 15;
    const int kb = l >> 4;
    const int nt = w & 1;
    const f16x8 A0 = *(const f16x8*)&xs16[nt * 16 + lr][kb * 8];
    const f16x8 A1 = *(const f16x8*)&xs16[nt * 16 + lr][32 + kb * 8];
    const int orow = n0 + nt * 16 + kb * 4;

    if (w < 2) {
        for (int ct = 0; ct < 8; ++ct) {
            const int col = ct * 16 + lr;
            const f16x8 B0 = *(const f16x8*)&Wt[col * 64 + kb * 8];
            const f16x8 B1 = *(const f16x8*)&Wt[col * 64 + 32 + kb * 8];
            f32x4 acc = {0.f, 0.f, 0.f, 0.f};
            acc = __builtin_amdgcn_mfma_f32_16x16x32_f16(A0, B0, acc, 0, 0, 0);
            acc = __builtin_amdgcn_mfma_f32_16x16x32_f16(A1, B1, acc, 0, 0, 0);
            const float bias = (col < 64) ? bfp[col] : bsp[col - 64];
            #pragma unroll
            for (int r = 0; r < 4; ++r)
                Pi[(size_t)(orow + r) * 128 + col] = acc[r] + bias;
        }
    } else {
        for (int pt = 0; pt < 4; ++pt) {
            const int colF = 128 + pt * 16 + lr;
            const int colS = 192 + pt * 16 + lr;
            const f16x8 BF0 = *(const f16x8*)&Wt[colF * 64 + kb * 8];
            const f16x8 BF1 = *(const f16x8*)&Wt[colF * 64 + 32 + kb * 8];
            const f16x8 BS0 = *(const f16x8*)&Wt[colS * 64 + kb * 8];
            const f16x8 BS1 = *(const f16x8*)&Wt[colS * 64 + 32 + kb * 8];
            f32x4 aF = {0.f, 0.f, 0.f, 0.f}, aS = {0.f, 0.f, 0.f, 0.f};
            aF = __builtin_amdgcn_mfma_f32_16x16x32_f16(A0, BF0, aF, 0, 0, 0);
            aF = __builtin_amdgcn_mfma_f32_16x16x32_f16(A1, BF1, aF, 0, 0, 0);
            aS = __builtin_amdgcn_mfma_f32_16x16x32_f16(A0, BS0, aS, 0, 0, 0);
            aS = __builtin_amdgcn_mfma_f32_16x16x32_f16(A1, BS1, aS, 0, 0, 0);
            const int cj = pt * 16 + lr;
            #pragma unroll
            for (int r = 0; r < 4; ++r)
                Pj16[(size_t)(orow + r) * 64 + cj] = __floats2half2_rn((float)aF[r], (float)aS[r]);
        }
    }
}

// ---------------- edge-parallel row-range conv (unchanged, at floor) ----------------
__launch_bounds__(256, 7)
__global__ void k_edge_range(const __half2* __restrict__ Pj,
                             const float* __restrict__ Pi,
                             const int2* __restrict__ rcP, const float4* __restrict__ ewP,
                             const float* __restrict__ wfe, const float* __restrict__ wse,
                             const int* __restrict__ rs,
                             const float* __restrict__ xin, float* __restrict__ out) {
    __shared__ __align__(16) float piS[8][128];
    __shared__ __align__(16) float accS[8][8][64];
    __shared__ int rsS[9];
    const int tid = threadIdx.x;
    const int hw = tid >> 5;
    const int hb = hw & 1;
    const int wv = tid >> 6;
    const int c2 = (tid & 31) * 2;
    const int r0 = blockIdx.x * 8;
    for (int i = tid; i < 1024; i += 256)
        piS[i >> 7][i & 127] = Pi[(size_t)r0 * 128 + i];
    for (int i = tid; i < 4096; i += 256)
        ((float*)accS)[i] = 0.f;
    if (tid < 9) rsS[tid] = rs[r0 + tid];
    __syncthreads();
    const float wf0a = wfe[c2],       wf0b = wfe[c2 + 1];
    const float wf1a = wfe[64 + c2],  wf1b = wfe[64 + c2 + 1];
    const float wf2a = wfe[128 + c2], wf2b = wfe[128 + c2 + 1];
    const float ws0a = wse[c2],       ws0b = wse[c2 + 1];
    const float ws1a = wse[64 + c2],  ws1b = wse[64 + c2 + 1];
    const float ws2a = wse[128 + c2], ws2b = wse[128 + c2 + 1];
    const int pbeg = rsS[0], pend = rsS[8];

#define EDGE_BODY(P)                                                              \
    {                                                                             \
        const int2 rc = rcP[P];                                                   \
        const float4 e = ewP[P];                                                  \
        const uint2 Jraw = *(const uint2*)&Pj[rc.y * 64 + c2];                    \
        const float2 Ja = __half22float2(*(const __half2*)&Jraw.x);               \
        const float2 Jb = __half22float2(*(const __half2*)&Jraw.y);               \
        const int row = rc.x - r0;                                                \
        const float2 pf = *(const float2*)&piS[row][c2];                          \
        const float2 ps = *(const float2*)&piS[row][64 + c2];                     \
        const float afa = pf.x + Ja.x + e.x * wf0a + e.y * wf1a + e.z * wf2a;     \
        const float asa = ps.x + Ja.y + e.x * ws0a + e.y * ws1a + e.z * ws2a;     \
        const float afb = pf.y + Jb.x + e.x * wf0b + e.y * wf1b + e.z * wf2b;     \
        const float asb = ps.y + Jb.y + e.x * ws0b + e.y * ws1b + e.z * ws2b;     \
        const float sga = 1.f / (1.f + __expf(-afa));                             \
        const float spa = (asa > 20.f) ? asa : __logf(1.f + __expf(asa));         \
        const float sgb = 1.f / (1.f + __expf(-afb));                             \
        const float spb = (asb > 20.f) ? asb : __logf(1.f + __expf(asb));         \
        float2 acc = *(const float2*)&accS[hw][row][c2];                          \
        acc.x = fmaf(sga, spa, acc.x);                                            \
        acc.y = fmaf(sgb, spb, acc.y);                                            \
        *(float2*)&accS[hw][row][c2] = acc;                                       \
    }

    int p0 = pbeg + 2 * wv;
    #pragma unroll 2
    for (; p0 + 2 <= pend; p0 += 8) {
        const int p = p0 + hb;
        EDGE_BODY(p)
    }
    {
        const int p = p0 + hb;
        if (p < pend) EDGE_BODY(p)
    }
#undef EDGE_BODY

    __syncthreads();
    for (int i = tid; i < 512; i += 256) {
        const int row = i >> 6, ch = i & 63;
        float s = 0.f;
        #pragma unroll
        for (int a = 0; a < 8; ++a) s += accS[a][row][ch];
        const int deg = rsS[row + 1] - rsS[row];
        const size_t o = (size_t)(r0 + row) * 64 + ch;
        out[o] = fmaxf(fmaf(s, 1.f / (float)max(deg, 1), xin[o]), 0.f);
    }
}

// ---------------- MFMA GRU: h = GRU(m, h) — register-combined gates ----------------
__global__ void k_gru_mfma(const float* __restrict__ m, float* __restrict__ h,
                           const _Float16* __restrict__ WtG,
                           const float* __restrict__ bih, const float* __restrict__ bhh) {
    __shared__ _Float16 ms16[32][72];
    __shared__ _Float16 hs16[32][72];
    __shared__ __align__(16) float hs32[32][64];
    const int tid = threadIdx.x;
    const int n0 = blockIdx.x * 32;
    {
        const int n = tid >> 3, k0 = (tid & 7) * 8;
        const float4 ma = *(const float4*)&m[(size_t)(n0 + n) * 64 + k0];
        const float4 mb = *(const float4*)&m[(size_t)(n0 + n) * 64 + k0 + 4];
        const float4 ha = *(const float4*)&h[(size_t)(n0 + n) * 64 + k0];
        const float4 hb = *(const float4*)&h[(size_t)(n0 + n) * 64 + k0 + 4];
        f16x8 mv, hv;
        mv[0] = (_Float16)ma.x; mv[1] = (_Float16)ma.y; mv[2] = (_Float16)ma.z; mv[3] = (_Float16)ma.w;
        mv[4] = (_Float16)mb.x; mv[5] = (_Float16)mb.y; mv[6] = (_Float16)mb.z; mv[7] = (_Float16)mb.w;
        hv[0] = (_Float16)ha.x; hv[1] = (_Float16)ha.y; hv[2] = (_Float16)ha.z; hv[3] = (_Float16)ha.w;
        hv[4] = (_Float16)hb.x; hv[5] = (_Float16)hb.y; hv[6] = (_Float16)hb.z; hv[7] = (_Float16)hb.w;
        *(f16x8*)&ms16[n][k0] = mv;
        *(f16x8*)&hs16[n][k0] = hv;
        *(float4*)&hs32[n][k0] = ha;
        *(float4*)&hs32[n][k0 + 4] = hb;
    }
    __syncthreads();
    const int l  = tid & 63;
    const int w  = tid >> 6;
    const int lr = l & 15;
    const int kb = l >> 4;
    const int nt = w & 1;        // node tile
    const int cg = w >> 1;       // channel-quarter group base: ct = cg, cg+2
    const f16x8 A0 = *(const f16x8*)&ms16[nt * 16 + lr][kb * 8];
    const f16x8 A1 = *(const f16x8*)&ms16[nt * 16 + lr][32 + kb * 8];
    const f16x8 H0 = *(const f16x8*)&hs16[nt * 16 + lr][kb * 8];
    const f16x8 H1 = *(const f16x8*)&hs16[nt * 16 + lr][32 + kb * 8];
    const int orow = n0 + nt * 16 + kb * 4;   // global node for reg r
    const int lrow = nt * 16 + kb * 4;        // block-local node for reg r

    #pragma unroll
    for (int t = 0; t < 2; ++t) {
        const int ct = cg + t * 2;            // 0..3
        const int c = ct * 16 + lr;           // channel 0..63
        // B-frags: gi from cols {c, 64+c, 128+c}; gh from cols {192+c, 256+c, 320+c}
        const f16x8 BiR0 = *(const f16x8*)&WtG[(c)       * 64 + kb * 8];
        const f16x8 BiR1 = *(const f16x8*)&WtG[(c)       * 64 + 32 + kb * 8];
        const f16x8 BiZ0 = *(const f16x8*)&WtG[(64 + c)  * 64 + kb * 8];
        const f16x8 BiZ1 = *(const f16x8*)&WtG[(64 + c)  * 64 + 32 + kb * 8];
        const f16x8 BiN0 = *(const f16x8*)&WtG[(128 + c) * 64 + kb * 8];
        const f16x8 BiN1 = *(const f16x8*)&WtG[(128 + c) * 64 + 32 + kb * 8];
        const f16x8 BhR0 = *(const f16x8*)&WtG[(192 + c) * 64 + kb * 8];
        const f16x8 BhR1 = *(const f16x8*)&WtG[(192 + c) * 64 + 32 + kb * 8];
        const f16x8 BhZ0 = *(const f16x8*)&WtG[(256 + c) * 64 + kb * 8];
        const f16x8 BhZ1 = *(const f16x8*)&WtG[(256 + c) * 64 + 32 + kb * 8];
        const f16x8 BhN0 = *(const f16x8*)&WtG[(320 + c) * 64 + kb * 8];
        const f16x8 BhN1 = *(const f16x8*)&WtG[(320 + c) * 64 + 32 + kb * 8];
        f32x4 aIR = {0,0,0,0}, aIZ = {0,0,0,0}, aIN = {0,0,0,0};
        f32x4 aHR = {0,0,0,0}, aHZ = {0,0,0,0}, aHN = {0,0,0,0};
        aIR = __builtin_amdgcn_mfma_f32_16x16x32_f16(A0, BiR0, aIR, 0, 0, 0);
        aIR = __builtin_amdgcn_mfma_f32_16x16x32_f16(A1, BiR1, aIR, 0, 0, 0);
        aIZ = __builtin_amdgcn_mfma_f32_16x16x32_f16(A0, BiZ0, aIZ, 0, 0, 0);
        aIZ = __builtin_amdgcn_mfma_f32_16x16x32_f16(A1, BiZ1, aIZ, 0, 0, 0);
        aIN = __builtin_amdgcn_mfma_f32_16x16x32_f16(A0, BiN0, aIN, 0, 0, 0);
        aIN = __builtin_amdgcn_mfma_f32_16x16x32_f16(A1, BiN1, aIN, 0, 0, 0);
        aHR = __builtin_amdgcn_mfma_f32_16x16x32_f16(H0, BhR0, aHR, 0, 0, 0);
        aHR = __builtin_amdgcn_mfma_f32_16x16x32_f16(H1, BhR1, aHR, 0, 0, 0);
        aHZ = __builtin_amdgcn_mfma_f32_16x16x32_f16(H0, BhZ0, aHZ, 0, 0, 0);
        aHZ = __builtin_amdgcn_mfma_f32_16x16x32_f16(H1, BhZ1, aHZ, 0, 0, 0);
        aHN = __builtin_amdgcn_mfma_f32_16x16x32_f16(H0, BhN0, aHN, 0, 0, 0);
        aHN = __builtin_amdgcn_mfma_f32_16x16x32_f16(H1, BhN1, aHN, 0, 0, 0);
        const float bir = bih[c], biz = bih[64 + c], bin = bih[128 + c];
        const float bhr = bhh[c], bhz = bhh[64 + c], bhn = bhh[128 + c];
        #pragma unroll
        for (int r = 0; r < 4; ++r) {
            const float rg = 1.f / (1.f + __expf(-(((float)aIR[r] + bir) + ((float)aHR[r] + bhr))));
            const float zg = 1.f / (1.f + __expf(-(((float)aIZ[r] + biz) + ((float)aHZ[r] + bhz))));
            const float ng = tanhf(((float)aIN[r] + bin) + rg * ((float)aHN[r] + bhn));
            h[(size_t)(orow + r) * 64 + c] = (1.f - zg) * ng + zg * hs32[lrow + r][c];
        }
    }
}

// ---------------- first-node-per-graph indices (searchsorted) ----------------
__global__ void k_idx(const int* __restrict__ batch, int* __restrict__ idx) {
    int g = threadIdx.x;
    if (g >= NGRAPH) return;
    int lo = 0, hi = NN;
    while (lo < hi) {
        int mid = (lo + hi) >> 1;
        if (batch[mid] < g) lo = mid + 1; else hi = mid;
    }
    idx[g] = lo;
}

// ---------------- readout head: all weights/activations in LDS ----------------
__global__ void k_head(const float* __restrict__ h, const int* __restrict__ idx,
                       const float* __restrict__ fcsw, const float* __restrict__ fcsb,
                       const float* __restrict__ f2cw, const float* __restrict__ f2cb,
                       const float* __restrict__ f3cw, const float* __restrict__ f3cb,
                       const float* __restrict__ f2dw, const float* __restrict__ f2db,
                       const float* __restrict__ f3dw, const float* __restrict__ f3db,
                       float* __restrict__ out) {
    __shared__ float hsB[4096];
    __shared__ float waB[4096];
    __shared__ float wbB[4096];
    __shared__ float wcB[4096];
    const int tid = threadIdx.x;
    for (int i = tid; i < 4096; i += 256) {
        int g = i >> 6, k = i & 63;
        hsB[i] = h[(size_t)idx[g] * 64 + k];
        waB[i] = fcsw[i];
        wbB[i] = f2cw[i];
        wcB[i] = f2dw[i];
    }
    __syncthreads();
    float v[16];
    #pragma unroll
    for (int j = 0; j < 16; ++j) {
        const int i = j * 256 + tid, g = i >> 6, c = i & 63;
        float a = fcsb[c];
        for (int k = 0; k < 64; ++k) a = fmaf(hsB[g * 64 + k], waB[k * 64 + c], a);
        v[j] = fmaxf(a, 0.f);
    }
    __syncthreads();
    #pragma unroll
    for (int j = 0; j < 16; ++j) hsB[j * 256 + tid] = v[j];
    __syncthreads();
    float vc[16], vd[16];
    #pragma unroll
    for (int j = 0; j < 16; ++j) {
        const int i = j * 256 + tid, g = i >> 6, c = i & 63;
        float a1 = f2cb[c], a2 = f2db[c];
        for (int k = 0; k < 64; ++k) {
            const float xv = hsB[g * 64 + k];
            a1 = fmaf(xv, wbB[k * 64 + c], a1);
            a2 = fmaf(xv, wcB[k * 64 + c], a2);
        }
        vc[j] = fmaxf(a1, 0.f);
        vd[j] = fmaxf(a2, 0.f);
    }
    __syncthreads();
    #pragma unroll
    for (int j = 0; j < 16; ++j) {
        waB[j * 256 + tid] = vc[j];
        wbB[j * 256 + tid] = vd[j];
    }
    if (tid < 128) wcB[tid] = f3cw[tid];
    else           wcB[tid] = f3dw[tid - 128];
    __syncthreads();
    if (tid < 128) {
        int g = tid >> 1, j = tid & 1;
        float a = f3cb[j];
        for (int k = 0; k < 64; ++k) a = fmaf(waB[g * 64 + k], wcB[k * 2 + j], a);
        out[g * 2 + j] = 1.f / (1.f + expf(-a));
    } else {
        int t = tid - 128, g = t >> 1, j = t & 1;
        float a = f3db[j];
        for (int k = 0; k < 64; ++k) a = fmaf(wbB[g * 64 + k], wcB[128 + k * 2 + j], a);
        out[128 + g * 2 + j] = a;
    }
}

// ---------------- host launcher ----------------
extern "C" void kernel_launch(void* const* d_in, const int* in_sizes, int n_in,
                              void* d_out, int out_size, void* d_ws, size_t ws_size,
                              hipStream_t stream) {
    (void)in_sizes; (void)n_in; (void)out_size; (void)ws_size;
    const float* x    = (const float*)d_in[0];
    const int* ei1    = (const int*)d_in[1];
    const int* ei2    = (const int*)d_in[2];
    const float* w1   = (const float*)d_in[3];
    const float* w2   = (const float*)d_in[4];
    const int* batch  = (const int*)d_in[5];
    const float* fc1w = (const float*)d_in[6];
    const float* fc1b = (const float*)d_in[7];
    const float* lfw  = (const float*)d_in[8];
    const float* lfb  = (const float*)d_in[9];
    const float* lsw  = (const float*)d_in[10];
    const float* lsb  = (const float*)d_in[11];
    const float* wih  = (const float*)d_in[12];
    const float* bih  = (const float*)d_in[13];
    const float* whh  = (const float*)d_in[14];
    const float* bhh  = (const float*)d_in[15];
    const float* fcsw = (const float*)d_in[16];
    const float* fcsb = (const float*)d_in[17];
    const float* f2cw = (const float*)d_in[18];
    const float* f2cb = (const float*)d_in[19];
    const float* f3cw = (const float*)d_in[20];
    const float* f3cb = (const float*)d_in[21];
    const float* f2dw = (const float*)d_in[22];
    const float* f2db = (const float*)d_in[23];
    const float* f3dw = (const float*)d_in[24];
    const float* f3db = (const float*)d_in[25];

    char* ws = (char*)d_ws;
    size_t off = 0;
    auto alloc = [&](size_t bytes) { char* p = ws + off; off += (bytes + 255) & ~size_t(255); return p; };
    float*   Pi    = (float*)alloc(size_t(NN) * 128 * 4);      // 20.5 MB
    __half2* Pj16  = (__half2*)alloc(size_t(NN) * 64 * 4);     // 10.2 MB
    float*   hbuf  = (float*)alloc(size_t(NN) * CD * 4);
    float*   mbuf  = (float*)alloc(size_t(NN) * CD * 4);
    _Float16* W16  = (_Float16*)alloc(256 * 64 * 2);           // 32 KB
    _Float16* WG16 = (_Float16*)alloc(384 * 64 * 2);           // 48 KB
    int*   cnt1  = (int*)alloc(size_t(NN) * 4);
    int*   cnt2  = (int*)alloc(size_t(NN) * 4);
    int*   rs1   = (int*)alloc(size_t(NN + 1) * 4);
    int*   rs2   = (int*)alloc(size_t(NN + 1) * 4);
    int*   cur1  = (int*)alloc(size_t(NN + 1) * 4);
    int*   cur2  = (int*)alloc(size_t(NN + 1) * 4);
    int*   perm1 = (int*)alloc(size_t(NE) * 4);
    int*   perm2 = (int*)alloc(size_t(NE) * 4);
    int2*  rcP1  = (int2*)alloc(size_t(NE) * 8);
    int2*  rcP2  = (int2*)alloc(size_t(NE) * 8);
    float4* ewP1 = (float4*)alloc(size_t(NE) * 16);
    float4* ewP2 = (float4*)alloc(size_t(NE) * 16);
    int*   part1 = (int*)alloc(256 * 4);
    int*   part2 = (int*)alloc(256 * 4);
    int*   offs1 = (int*)alloc(256 * 4);
    int*   offs2 = (int*)alloc(256 * 4);
    int*   idx   = (int*)alloc(256);

    const int NB_NC = (NN * CD + 255) / 256;
    const int EDGE_BLOCKS = NN / 8;     // 5000
    const int PROJ_BLOCKS = NN / 32;    // 1250
    const int GRU_BLOCKS  = NN / 32;    // 1250

    const float* lfe = lfw + 128 * 64;
    const float* lse = lsw + 128 * 64;

    // CSR build + one-time f16 weight transposes
    hipMemsetAsync(cnt1, 0, size_t(NN) * 4 * 2 + 256, stream);
    k_count2<<<2 * EBLK, 256, 0, stream>>>(ei1, ei2, cnt1, cnt2);
    k_scan_part2<<<2 * SCAN_BLOCKS, 256, 0, stream>>>(cnt1, cnt2, part1, part2);
    k_scan_mid2<<<2, 256, 0, stream>>>(part1, part2, offs1, offs2);
    k_scan_fill2<<<2 * SCAN_BLOCKS, 256, 0, stream>>>(cnt1, cnt2, offs1, offs2, rs1, rs2, cur1, cur2);
    k_scatter2<<<2 * EBLK, 256, 0, stream>>>(ei1, ei2, cur1, cur2, perm1, perm2);
    k_edge_gather2<<<2 * EBLK, 256, 0, stream>>>(ei1, ei2, w1, w2, perm1, perm2,
                                                 rcP1, rcP2, ewP1, ewP2);
    k_wt16<<<64, 256, 0, stream>>>(lfw, lsw, W16);
    k_wtg16<<<96, 256, 0, stream>>>(wih, whh, WG16);

    k_fc1<<<NB_NC, 256, 0, stream>>>(x, fc1w, fc1b, hbuf);

    for (int it = 0; it < 3; ++it) {
        k_proj_mfma<<<PROJ_BLOCKS, 256, 0, stream>>>(hbuf, W16, lfb, lsb, Pi, Pj16);
        k_edge_range<<<EDGE_BLOCKS, 256, 0, stream>>>(Pj16, Pi, rcP2, ewP2,
                                                      lfe, lse, rs2, hbuf, mbuf);
        k_proj_mfma<<<PROJ_BLOCKS, 256, 0, stream>>>(mbuf, W16, lfb, lsb, Pi, Pj16);
        k_edge_range<<<EDGE_BLOCKS, 256, 0, stream>>>(Pj16, Pi, rcP1, ewP1,
                                                      lfe, lse, rs1, mbuf, mbuf);
        k_gru_mfma<<<GRU_BLOCKS, 256, 0, stream>>>(mbuf, hbuf, WG16, bih, bhh);
    }

    k_idx<<<1, 64, 0, stream>>>(batch, idx);
    k_head<<<1, 256, 0, stream>>>(hbuf, idx, fcsw, fcsb, f2cw, f2cb, f3cw, f3cb,
                                  f2dw, f2db, f3dw, f3db, (float*)d_out);
}

// Round 20
// 563.196 us; speedup vs baseline: 1.4013x; 1.0487x over previous
//
#include <hip/hip_runtime.h>
#include <hip/hip_bf16.h>
#include <hip/hip_fp16.h>
#include <math.h>

constexpr int NE = 400000;
constexpr int NN = 40000;
constexpr int CD = 64;
constexpr int NGRAPH = 64;
constexpr int SCAN_BLOCKS = (NN + 255) / 256;   // 157
constexpr int EBLK = (NE + 255) / 256;          // 1563

typedef _Float16 f16x8 __attribute__((ext_vector_type(8)));
typedef float f32x4 __attribute__((ext_vector_type(4)));

// ---------------- fc1: x0 = relu(x @ fc1_w + b) ----------------
__global__ void k_fc1(const float* __restrict__ x,
                      const float* __restrict__ w,
                      const float* __restrict__ b,
                      float* __restrict__ out) {
    int i = blockIdx.x * 256 + threadIdx.x;
    if (i >= NN * CD) return;
    int n = i >> 6, c = i & 63;
    float acc = b[c];
    #pragma unroll
    for (int k = 0; k < 9; ++k)
        acc = fmaf(x[n * 9 + k], w[k * 64 + c], acc);
    out[i] = fmaxf(acc, 0.f);
}

// ---------------- edge counts, both sets ----------------
__global__ void k_count2(const int* __restrict__ ei1, const int* __restrict__ ei2,
                         int* __restrict__ cnt1, int* __restrict__ cnt2) {
    const int b = blockIdx.x;
    const bool s2 = (b >= EBLK);
    const int* ei = s2 ? ei2 : ei1;
    int* cnt = s2 ? cnt2 : cnt1;
    int e = (s2 ? b - EBLK : b) * 256 + threadIdx.x;
    if (e >= NE) return;
    atomicAdd(&cnt[ei[e]], 1);
}

// ---------------- parallel scan phase 1, both sets ----------------
__global__ void k_scan_part2(const int* __restrict__ cnt1, const int* __restrict__ cnt2,
                             int* __restrict__ part1, int* __restrict__ part2) {
    __shared__ int red[256];
    const int b = blockIdx.x;
    const bool s2 = (b >= SCAN_BLOCKS);
    const int* cnt = s2 ? cnt2 : cnt1;
    int* partials = s2 ? part2 : part1;
    const int bb = s2 ? b - SCAN_BLOCKS : b;
    const int tid = threadIdx.x;
    const int i = bb * 256 + tid;
    red[tid] = (i < NN) ? cnt[i] : 0;
    __syncthreads();
    for (int s = 128; s > 0; s >>= 1) {
        if (tid < s) red[tid] += red[tid + s];
        __syncthreads();
    }
    if (tid == 0) partials[bb] = red[0];
}

// ---------------- phase 2, both sets (2 blocks) ----------------
__global__ void k_scan_mid2(const int* __restrict__ part1, const int* __restrict__ part2,
                            int* __restrict__ offs1, int* __restrict__ offs2) {
    __shared__ int part[256];
    const bool s2 = (blockIdx.x == 1);
    const int* partials = s2 ? part2 : part1;
    int* offs = s2 ? offs2 : offs1;
    const int tid = threadIdx.x;
    const int v = (tid < SCAN_BLOCKS) ? partials[tid] : 0;
    part[tid] = v;
    __syncthreads();
    for (int off = 1; off < 256; off <<= 1) {
        int t = (tid >= off) ? part[tid - off] : 0;
        __syncthreads();
        part[tid] += t;
        __syncthreads();
    }
    if (tid < SCAN_BLOCKS) offs[tid] = part[tid] - v;
}

// ---------------- phase 3, both sets ----------------
__global__ void k_scan_fill2(const int* __restrict__ cnt1, const int* __restrict__ cnt2,
                             const int* __restrict__ offs1, const int* __restrict__ offs2,
                             int* __restrict__ rs1, int* __restrict__ rs2,
                             int* __restrict__ cur1, int* __restrict__ cur2) {
    __shared__ int part[256];
    const int b = blockIdx.x;
    const bool s2 = (b >= SCAN_BLOCKS);
    const int* cnt = s2 ? cnt2 : cnt1;
    const int* offs = s2 ? offs2 : offs1;
    int* row_start = s2 ? rs2 : rs1;
    int* cursor = s2 ? cur2 : cur1;
    const int bb = s2 ? b - SCAN_BLOCKS : b;
    const int tid = threadIdx.x;
    const int i = bb * 256 + tid;
    const int v = (i < NN) ? cnt[i] : 0;
    part[tid] = v;
    __syncthreads();
    for (int off = 1; off < 256; off <<= 1) {
        int t = (tid >= off) ? part[tid - off] : 0;
        __syncthreads();
        part[tid] += t;
        __syncthreads();
    }
    const int excl = part[tid] - v + offs[bb];
    if (i < NN) { row_start[i] = excl; cursor[i] = excl; }
    if (i == NN - 1) row_start[NN] = NE;
}

// ---------------- merged scatter+gather: write packed CSR edge data directly ----------------
__global__ void k_scatgath2(const int* __restrict__ ei1, const int* __restrict__ ei2,
                            const float* __restrict__ w1, const float* __restrict__ w2,
                            int* __restrict__ cur1, int* __restrict__ cur2,
                            int2* __restrict__ rcP1, int2* __restrict__ rcP2,
                            float4* __restrict__ ewP1, float4* __restrict__ ewP2) {
    const int b = blockIdx.x;
    const bool s2 = (b >= EBLK);
    const int* ei = s2 ? ei2 : ei1;
    const float* ew = s2 ? w2 : w1;
    int* cursor = s2 ? cur2 : cur1;
    int2* rcP = s2 ? rcP2 : rcP1;
    float4* ewP = s2 ? ewP2 : ewP1;
    int e = (s2 ? b - EBLK : b) * 256 + threadIdx.x;
    if (e >= NE) return;
    const int r = ei[e];
    const int c = ei[NE + e];
    const int pos = atomicAdd(&cursor[r], 1);
    rcP[pos] = make_int2(r, c);
    ewP[pos] = make_float4(ew[3 * e], ew[3 * e + 1], ew[3 * e + 2], 0.f);
}

// ---------------- one-time: Wt[c][k] = f16(W_big[k][c]) (CGConv weights) ----------------
__global__ void k_wt16(const float* __restrict__ lfw, const float* __restrict__ lsw,
                       _Float16* __restrict__ Wt) {
    const int k = blockIdx.x;       // 0..63
    const int c = threadIdx.x;      // 0..255
    float v;
    if (c < 64)       v = lfw[k * 64 + c];
    else if (c < 128) v = lsw[k * 64 + (c - 64)];
    else if (c < 192) v = lfw[(64 + k) * 64 + (c - 128)];
    else              v = lsw[(64 + k) * 64 + (c - 192)];
    Wt[c * 64 + k] = (_Float16)v;
}

// ---------------- one-time: WtG[c][k] f16 — GRU weights (0..191 wih, 192..383 whh) ----------------
__global__ void k_wtg16(const float* __restrict__ wih, const float* __restrict__ whh,
                        _Float16* __restrict__ WtG) {
    const int i = blockIdx.x * 256 + threadIdx.x;   // 0..24575
    const int c = i >> 6, k = i & 63;
    const float v = (c < 192) ? wih[k * 192 + c] : whh[k * 192 + (c - 192)];
    WtG[c * 64 + k] = (_Float16)v;
}

// ---------------- MFMA node projection: P = X @ W_big (f16 in, f32 acc) ----------------
__launch_bounds__(256, 4)
__global__ void k_proj_mfma(const float* __restrict__ x,
                            const _Float16* __restrict__ Wt,
                            const float* __restrict__ bfp, const float* __restrict__ bsp,
                            float* __restrict__ Pi, __half2* __restrict__ Pj16) {
    __shared__ _Float16 xs16[32][72];
    const int tid = threadIdx.x;
    const int n0 = blockIdx.x * 32;
    {
        const int n = tid >> 3, k0 = (tid & 7) * 8;
        const float4 a = *(const float4*)&x[(size_t)(n0 + n) * 64 + k0];
        const float4 b = *(const float4*)&x[(size_t)(n0 + n) * 64 + k0 + 4];
        f16x8 v;
        v[0] = (_Float16)a.x; v[1] = (_Float16)a.y; v[2] = (_Float16)a.z; v[3] = (_Float16)a.w;
        v[4] = (_Float16)b.x; v[5] = (_Float16)b.y; v[6] = (_Float16)b.z; v[7] = (_Float16)b.w;
        *(f16x8*)&xs16[n][k0] = v;
    }
    __syncthreads();
    const int l  = tid & 63;
    const int w  = tid >> 6;
    const int lr = l & 15;
    const int kb = l >> 4;
    const int nt = w & 1;
    const f16x8 A0 = *(const f16x8*)&xs16[nt * 16 + lr][kb * 8];
    const f16x8 A1 = *(const f16x8*)&xs16[nt * 16 + lr][32 + kb * 8];
    const int orow = n0 + nt * 16 + kb * 4;

    if (w < 2) {
        for (int ct = 0; ct < 8; ++ct) {
            const int col = ct * 16 + lr;
            const f16x8 B0 = *(const f16x8*)&Wt[col * 64 + kb * 8];
            const f16x8 B1 = *(const f16x8*)&Wt[col * 64 + 32 + kb * 8];
            f32x4 acc = {0.f, 0.f, 0.f, 0.f};
            acc = __builtin_amdgcn_mfma_f32_16x16x32_f16(A0, B0, acc, 0, 0, 0);
            acc = __builtin_amdgcn_mfma_f32_16x16x32_f16(A1, B1, acc, 0, 0, 0);
            const float bias = (col < 64) ? bfp[col] : bsp[col - 64];
            #pragma unroll
            for (int r = 0; r < 4; ++r)
                Pi[(size_t)(orow + r) * 128 + col] = acc[r] + bias;
        }
    } else {
        for (int pt = 0; pt < 4; ++pt) {
            const int colF = 128 + pt * 16 + lr;
            const int colS = 192 + pt * 16 + lr;
            const f16x8 BF0 = *(const f16x8*)&Wt[colF * 64 + kb * 8];
            const f16x8 BF1 = *(const f16x8*)&Wt[colF * 64 + 32 + kb * 8];
            const f16x8 BS0 = *(const f16x8*)&Wt[colS * 64 + kb * 8];
            const f16x8 BS1 = *(const f16x8*)&Wt[colS * 64 + 32 + kb * 8];
            f32x4 aF = {0.f, 0.f, 0.f, 0.f}, aS = {0.f, 0.f, 0.f, 0.f};
            aF = __builtin_amdgcn_mfma_f32_16x16x32_f16(A0, BF0, aF, 0, 0, 0);
            aF = __builtin_amdgcn_mfma_f32_16x16x32_f16(A1, BF1, aF, 0, 0, 0);
            aS = __builtin_amdgcn_mfma_f32_16x16x32_f16(A0, BS0, aS, 0, 0, 0);
            aS = __builtin_amdgcn_mfma_f32_16x16x32_f16(A1, BS1, aS, 0, 0, 0);
            const int cj = pt * 16 + lr;
            #pragma unroll
            for (int r = 0; r < 4; ++r)
                Pj16[(size_t)(orow + r) * 64 + cj] = __floats2half2_rn((float)aF[r], (float)aS[r]);
        }
    }
}

// ---------------- edge-parallel row-range conv: half2 row staging, 8 blocks/CU ----------------
__launch_bounds__(256, 8)
__global__ void k_edge_range(const __half2* __restrict__ Pj,
                             const float* __restrict__ Pi,
                             const int2* __restrict__ rcP, const float4* __restrict__ ewP,
                             const float* __restrict__ wfe, const float* __restrict__ wse,
                             const int* __restrict__ rs,
                             const float* __restrict__ xin, float* __restrict__ out) {
    __shared__ __align__(8) __half2 piH[8][64];     // (pf,ps) per channel, 2 KB
    __shared__ __align__(16) float accS[8][8][64];  // 16 KB
    __shared__ int rsS[9];
    const int tid = threadIdx.x;
    const int hw = tid >> 5;
    const int hb = hw & 1;
    const int wv = tid >> 6;
    const int c2 = (tid & 31) * 2;
    const int r0 = blockIdx.x * 8;
    for (int i = tid; i < 512; i += 256) {
        const int row = i >> 6, ch = i & 63;
        piH[row][ch] = __floats2half2_rn(Pi[(size_t)(r0 + row) * 128 + ch],
                                         Pi[(size_t)(r0 + row) * 128 + 64 + ch]);
    }
    for (int i = tid; i < 4096; i += 256)
        ((float*)accS)[i] = 0.f;
    if (tid < 9) rsS[tid] = rs[r0 + tid];
    __syncthreads();
    const float wf0a = wfe[c2],       wf0b = wfe[c2 + 1];
    const float wf1a = wfe[64 + c2],  wf1b = wfe[64 + c2 + 1];
    const float wf2a = wfe[128 + c2], wf2b = wfe[128 + c2 + 1];
    const float ws0a = wse[c2],       ws0b = wse[c2 + 1];
    const float ws1a = wse[64 + c2],  ws1b = wse[64 + c2 + 1];
    const float ws2a = wse[128 + c2], ws2b = wse[128 + c2 + 1];
    const int pbeg = rsS[0], pend = rsS[8];

#define EDGE_BODY(P)                                                              \
    {                                                                             \
        const int2 rc = rcP[P];                                                   \
        const float4 e = ewP[P];                                                  \
        const uint2 Jraw = *(const uint2*)&Pj[rc.y * 64 + c2];                    \
        const float2 Ja = __half22float2(*(const __half2*)&Jraw.x);               \
        const float2 Jb = __half22float2(*(const __half2*)&Jraw.y);               \
        const int row = rc.x - r0;                                                \
        const uint2 PH = *(const uint2*)&piH[row][c2];                            \
        const float2 Pa = __half22float2(*(const __half2*)&PH.x);                 \
        const float2 Pb = __half22float2(*(const __half2*)&PH.y);                 \
        const float afa = Pa.x + Ja.x + e.x * wf0a + e.y * wf1a + e.z * wf2a;     \
        const float asa = Pa.y + Ja.y + e.x * ws0a + e.y * ws1a + e.z * ws2a;     \
        const float afb = Pb.x + Jb.x + e.x * wf0b + e.y * wf1b + e.z * wf2b;     \
        const float asb = Pb.y + Jb.y + e.x * ws0b + e.y * ws1b + e.z * ws2b;     \
        const float sga = 1.f / (1.f + __expf(-afa));                             \
        const float spa = (asa > 20.f) ? asa : __logf(1.f + __expf(asa));         \
        const float sgb = 1.f / (1.f + __expf(-afb));                             \
        const float spb = (asb > 20.f) ? asb : __logf(1.f + __expf(asb));         \
        float2 acc = *(const float2*)&accS[hw][row][c2];                          \
        acc.x = fmaf(sga, spa, acc.x);                                            \
        acc.y = fmaf(sgb, spb, acc.y);                                            \
        *(float2*)&accS[hw][row][c2] = acc;                                       \
    }

    int p0 = pbeg + 2 * wv;
    #pragma unroll 2
    for (; p0 + 2 <= pend; p0 += 8) {
        const int p = p0 + hb;
        EDGE_BODY(p)
    }
    {
        const int p = p0 + hb;
        if (p < pend) EDGE_BODY(p)
    }
#undef EDGE_BODY

    __syncthreads();
    for (int i = tid; i < 512; i += 256) {
        const int row = i >> 6, ch = i & 63;
        float s = 0.f;
        #pragma unroll
        for (int a = 0; a < 8; ++a) s += accS[a][row][ch];
        const int deg = rsS[row + 1] - rsS[row];
        const size_t o = (size_t)(r0 + row) * 64 + ch;
        out[o] = fmaxf(fmaf(s, 1.f / (float)max(deg, 1), xin[o]), 0.f);
    }
}

// ---------------- MFMA GRU: h = GRU(m, h) — register-combined gates ----------------
__global__ void k_gru_mfma(const float* __restrict__ m, float* __restrict__ h,
                           const _Float16* __restrict__ WtG,
                           const float* __restrict__ bih, const float* __restrict__ bhh) {
    __shared__ _Float16 ms16[32][72];
    __shared__ _Float16 hs16[32][72];
    __shared__ __align__(16) float hs32[32][64];
    const int tid = threadIdx.x;
    const int n0 = blockIdx.x * 32;
    {
        const int n = tid >> 3, k0 = (tid & 7) * 8;
        const float4 ma = *(const float4*)&m[(size_t)(n0 + n) * 64 + k0];
        const float4 mb = *(const float4*)&m[(size_t)(n0 + n) * 64 + k0 + 4];
        const float4 ha = *(const float4*)&h[(size_t)(n0 + n) * 64 + k0];
        const float4 hb = *(const float4*)&h[(size_t)(n0 + n) * 64 + k0 + 4];
        f16x8 mv, hv;
        mv[0] = (_Float16)ma.x; mv[1] = (_Float16)ma.y; mv[2] = (_Float16)ma.z; mv[3] = (_Float16)ma.w;
        mv[4] = (_Float16)mb.x; mv[5] = (_Float16)mb.y; mv[6] = (_Float16)mb.z; mv[7] = (_Float16)mb.w;
        hv[0] = (_Float16)ha.x; hv[1] = (_Float16)ha.y; hv[2] = (_Float16)ha.z; hv[3] = (_Float16)ha.w;
        hv[4] = (_Float16)hb.x; hv[5] = (_Float16)hb.y; hv[6] = (_Float16)hb.z; hv[7] = (_Float16)hb.w;
        *(f16x8*)&ms16[n][k0] = mv;
        *(f16x8*)&hs16[n][k0] = hv;
        *(float4*)&hs32[n][k0] = ha;
        *(float4*)&hs32[n][k0 + 4] = hb;
    }
    __syncthreads();
    const int l  = tid & 63;
    const int w  = tid >> 6;
    const int lr = l & 15;
    const int kb = l >> 4;
    const int nt = w & 1;
    const int cg = w >> 1;
    const f16x8 A0 = *(const f16x8*)&ms16[nt * 16 + lr][kb * 8];
    const f16x8 A1 = *(const f16x8*)&ms16[nt * 16 + lr][32 + kb * 8];
    const f16x8 H0 = *(const f16x8*)&hs16[nt * 16 + lr][kb * 8];
    const f16x8 H1 = *(const f16x8*)&hs16[nt * 16 + lr][32 + kb * 8];
    const int orow = n0 + nt * 16 + kb * 4;
    const int lrow = nt * 16 + kb * 4;

    #pragma unroll
    for (int t = 0; t < 2; ++t) {
        const int ct = cg + t * 2;
        const int c = ct * 16 + lr;
        const f16x8 BiR0 = *(const f16x8*)&WtG[(c)       * 64 + kb * 8];
        const f16x8 BiR1 = *(const f16x8*)&WtG[(c)       * 64 + 32 + kb * 8];
        const f16x8 BiZ0 = *(const f16x8*)&WtG[(64 + c)  * 64 + kb * 8];
        const f16x8 BiZ1 = *(const f16x8*)&WtG[(64 + c)  * 64 + 32 + kb * 8];
        const f16x8 BiN0 = *(const f16x8*)&WtG[(128 + c) * 64 + kb * 8];
        const f16x8 BiN1 = *(const f16x8*)&WtG[(128 + c) * 64 + 32 + kb * 8];
        const f16x8 BhR0 = *(const f16x8*)&WtG[(192 + c) * 64 + kb * 8];
        const f16x8 BhR1 = *(const f16x8*)&WtG[(192 + c) * 64 + 32 + kb * 8];
        const f16x8 BhZ0 = *(const f16x8*)&WtG[(256 + c) * 64 + kb * 8];
        const f16x8 BhZ1 = *(const f16x8*)&WtG[(256 + c) * 64 + 32 + kb * 8];
        const f16x8 BhN0 = *(const f16x8*)&WtG[(320 + c) * 64 + kb * 8];
        const f16x8 BhN1 = *(const f16x8*)&WtG[(320 + c) * 64 + 32 + kb * 8];
        f32x4 aIR = {0,0,0,0}, aIZ = {0,0,0,0}, aIN = {0,0,0,0};
        f32x4 aHR = {0,0,0,0}, aHZ = {0,0,0,0}, aHN = {0,0,0,0};
        aIR = __builtin_amdgcn_mfma_f32_16x16x32_f16(A0, BiR0, aIR, 0, 0, 0);
        aIR = __builtin_amdgcn_mfma_f32_16x16x32_f16(A1, BiR1, aIR, 0, 0, 0);
        aIZ = __builtin_amdgcn_mfma_f32_16x16x32_f16(A0, BiZ0, aIZ, 0, 0, 0);
        aIZ = __builtin_amdgcn_mfma_f32_16x16x32_f16(A1, BiZ1, aIZ, 0, 0, 0);
        aIN = __builtin_amdgcn_mfma_f32_16x16x32_f16(A0, BiN0, aIN, 0, 0, 0);
        aIN = __builtin_amdgcn_mfma_f32_16x16x32_f16(A1, BiN1, aIN, 0, 0, 0);
        aHR = __builtin_amdgcn_mfma_f32_16x16x32_f16(H0, BhR0, aHR, 0, 0, 0);
        aHR = __builtin_amdgcn_mfma_f32_16x16x32_f16(H1, BhR1, aHR, 0, 0, 0);
        aHZ = __builtin_amdgcn_mfma_f32_16x16x32_f16(H0, BhZ0, aHZ, 0, 0, 0);
        aHZ = __builtin_amdgcn_mfma_f32_16x16x32_f16(H1, BhZ1, aHZ, 0, 0, 0);
        aHN = __builtin_amdgcn_mfma_f32_16x16x32_f16(H0, BhN0, aHN, 0, 0, 0);
        aHN = __builtin_amdgcn_mfma_f32_16x16x32_f16(H1, BhN1, aHN, 0, 0, 0);
        const float bir = bih[c], biz = bih[64 + c], bin = bih[128 + c];
        const float bhr = bhh[c], bhz = bhh[64 + c], bhn = bhh[128 + c];
        #pragma unroll
        for (int r = 0; r < 4; ++r) {
            const float rg = 1.f / (1.f + __expf(-(((float)aIR[r] + bir) + ((float)aHR[r] + bhr))));
            const float zg = 1.f / (1.f + __expf(-(((float)aIZ[r] + biz) + ((float)aHZ[r] + bhz))));
            const float ng = tanhf(((float)aIN[r] + bin) + rg * ((float)aHN[r] + bhn));
            h[(size_t)(orow + r) * 64 + c] = (1.f - zg) * ng + zg * hs32[lrow + r][c];
        }
    }
}

// ---------------- readout head (idx fused in) ----------------
__global__ void k_head(const float* __restrict__ h, const int* __restrict__ batch,
                       const float* __restrict__ fcsw, const float* __restrict__ fcsb,
                       const float* __restrict__ f2cw, const float* __restrict__ f2cb,
                       const float* __restrict__ f3cw, const float* __restrict__ f3cb,
                       const float* __restrict__ f2dw, const float* __restrict__ f2db,
                       const float* __restrict__ f3dw, const float* __restrict__ f3db,
                       float* __restrict__ out) {
    __shared__ float hsB[4096];
    __shared__ float waB[4096];
    __shared__ float wbB[4096];
    __shared__ float wcB[4096];
    __shared__ int sidx[64];
    const int tid = threadIdx.x;
    if (tid < 64) {
        int lo = 0, hi = NN;
        while (lo < hi) {
            int mid = (lo + hi) >> 1;
            if (batch[mid] < tid) lo = mid + 1; else hi = mid;
        }
        sidx[tid] = lo;
    }
    __syncthreads();
    for (int i = tid; i < 4096; i += 256) {
        int g = i >> 6, k = i & 63;
        hsB[i] = h[(size_t)sidx[g] * 64 + k];
        waB[i] = fcsw[i];
        wbB[i] = f2cw[i];
        wcB[i] = f2dw[i];
    }
    __syncthreads();
    float v[16];
    #pragma unroll
    for (int j = 0; j < 16; ++j) {
        const int i = j * 256 + tid, g = i >> 6, c = i & 63;
        float a = fcsb[c];
        for (int k = 0; k < 64; ++k) a = fmaf(hsB[g * 64 + k], waB[k * 64 + c], a);
        v[j] = fmaxf(a, 0.f);
    }
    __syncthreads();
    #pragma unroll
    for (int j = 0; j < 16; ++j) hsB[j * 256 + tid] = v[j];
    __syncthreads();
    float vc[16], vd[16];
    #pragma unroll
    for (int j = 0; j < 16; ++j) {
        const int i = j * 256 + tid, g = i >> 6, c = i & 63;
        float a1 = f2cb[c], a2 = f2db[c];
        for (int k = 0; k < 64; ++k) {
            const float xv = hsB[g * 64 + k];
            a1 = fmaf(xv, wbB[k * 64 + c], a1);
            a2 = fmaf(xv, wcB[k * 64 + c], a2);
        }
        vc[j] = fmaxf(a1, 0.f);
        vd[j] = fmaxf(a2, 0.f);
    }
    __syncthreads();
    #pragma unroll
    for (int j = 0; j < 16; ++j) {
        waB[j * 256 + tid] = vc[j];
        wbB[j * 256 + tid] = vd[j];
    }
    if (tid < 128) wcB[tid] = f3cw[tid];
    else           wcB[tid] = f3dw[tid - 128];
    __syncthreads();
    if (tid < 128) {
        int g = tid >> 1, j = tid & 1;
        float a = f3cb[j];
        for (int k = 0; k < 64; ++k) a = fmaf(waB[g * 64 + k], wcB[k * 2 + j], a);
        out[g * 2 + j] = 1.f / (1.f + expf(-a));
    } else {
        int t = tid - 128, g = t >> 1, j = t & 1;
        float a = f3db[j];
        for (int k = 0; k < 64; ++k) a = fmaf(wbB[g * 64 + k], wcB[128 + k * 2 + j], a);
        out[128 + g * 2 + j] = a;
    }
}

// ---------------- host launcher ----------------
extern "C" void kernel_launch(void* const* d_in, const int* in_sizes, int n_in,
                              void* d_out, int out_size, void* d_ws, size_t ws_size,
                              hipStream_t stream) {
    (void)in_sizes; (void)n_in; (void)out_size; (void)ws_size;
    const float* x    = (const float*)d_in[0];
    const int* ei1    = (const int*)d_in[1];
    const int* ei2    = (const int*)d_in[2];
    const float* w1   = (const float*)d_in[3];
    const float* w2   = (const float*)d_in[4];
    const int* batch  = (const int*)d_in[5];
    const float* fc1w = (const float*)d_in[6];
    const float* fc1b = (const float*)d_in[7];
    const float* lfw  = (const float*)d_in[8];
    const float* lfb  = (const float*)d_in[9];
    const float* lsw  = (const float*)d_in[10];
    const float* lsb  = (const float*)d_in[11];
    const float* wih  = (const float*)d_in[12];
    const float* bih  = (const float*)d_in[13];
    const float* whh  = (const float*)d_in[14];
    const float* bhh  = (const float*)d_in[15];
    const float* fcsw = (const float*)d_in[16];
    const float* fcsb = (const float*)d_in[17];
    const float* f2cw = (const float*)d_in[18];
    const float* f2cb = (const float*)d_in[19];
    const float* f3cw = (const float*)d_in[20];
    const float* f3cb = (const float*)d_in[21];
    const float* f2dw = (const float*)d_in[22];
    const float* f2db = (const float*)d_in[23];
    const float* f3dw = (const float*)d_in[24];
    const float* f3db = (const float*)d_in[25];

    char* ws = (char*)d_ws;
    size_t off = 0;
    auto alloc = [&](size_t bytes) { char* p = ws + off; off += (bytes + 255) & ~size_t(255); return p; };
    float*   Pi    = (float*)alloc(size_t(NN) * 128 * 4);      // 20.5 MB
    __half2* Pj16  = (__half2*)alloc(size_t(NN) * 64 * 4);     // 10.2 MB
    float*   hbuf  = (float*)alloc(size_t(NN) * CD * 4);
    float*   mbuf  = (float*)alloc(size_t(NN) * CD * 4);
    _Float16* W16  = (_Float16*)alloc(256 * 64 * 2);           // 32 KB
    _Float16* WG16 = (_Float16*)alloc(384 * 64 * 2);           // 48 KB
    int*   cnt1  = (int*)alloc(size_t(NN) * 4);
    int*   cnt2  = (int*)alloc(size_t(NN) * 4);
    int*   rs1   = (int*)alloc(size_t(NN + 1) * 4);
    int*   rs2   = (int*)alloc(size_t(NN + 1) * 4);
    int*   cur1  = (int*)alloc(size_t(NN + 1) * 4);
    int*   cur2  = (int*)alloc(size_t(NN + 1) * 4);
    int2*  rcP1  = (int2*)alloc(size_t(NE) * 8);
    int2*  rcP2  = (int2*)alloc(size_t(NE) * 8);
    float4* ewP1 = (float4*)alloc(size_t(NE) * 16);
    float4* ewP2 = (float4*)alloc(size_t(NE) * 16);
    int*   part1 = (int*)alloc(256 * 4);
    int*   part2 = (int*)alloc(256 * 4);
    int*   offs1 = (int*)alloc(256 * 4);
    int*   offs2 = (int*)alloc(256 * 4);

    const int NB_NC = (NN * CD + 255) / 256;
    const int EDGE_BLOCKS = NN / 8;     // 5000
    const int PROJ_BLOCKS = NN / 32;    // 1250
    const int GRU_BLOCKS  = NN / 32;    // 1250

    const float* lfe = lfw + 128 * 64;
    const float* lse = lsw + 128 * 64;

    // CSR build + one-time f16 weight transposes
    hipMemsetAsync(cnt1, 0, size_t(NN) * 4 * 2 + 256, stream);
    k_count2<<<2 * EBLK, 256, 0, stream>>>(ei1, ei2, cnt1, cnt2);
    k_scan_part2<<<2 * SCAN_BLOCKS, 256, 0, stream>>>(cnt1, cnt2, part1, part2);
    k_scan_mid2<<<2, 256, 0, stream>>>(part1, part2, offs1, offs2);
    k_scan_fill2<<<2 * SCAN_BLOCKS, 256, 0, stream>>>(cnt1, cnt2, offs1, offs2, rs1, rs2, cur1, cur2);
    k_scatgath2<<<2 * EBLK, 256, 0, stream>>>(ei1, ei2, w1, w2, cur1, cur2,
                                              rcP1, rcP2, ewP1, ewP2);
    k_wt16<<<64, 256, 0, stream>>>(lfw, lsw, W16);
    k_wtg16<<<96, 256, 0, stream>>>(wih, whh, WG16);

    k_fc1<<<NB_NC, 256, 0, stream>>>(x, fc1w, fc1b, hbuf);

    for (int it = 0; it < 3; ++it) {
        k_proj_mfma<<<PROJ_BLOCKS, 256, 0, stream>>>(hbuf, W16, lfb, lsb, Pi, Pj16);
        k_edge_range<<<EDGE_BLOCKS, 256, 0, stream>>>(Pj16, Pi, rcP2, ewP2,
                                                      lfe, lse, rs2, hbuf, mbuf);
        k_proj_mfma<<<PROJ_BLOCKS, 256, 0, stream>>>(mbuf, W16, lfb, lsb, Pi, Pj16);
        k_edge_range<<<EDGE_BLOCKS, 256, 0, stream>>>(Pj16, Pi, rcP1, ewP1,
                                                      lfe, lse, rs1, mbuf, mbuf);
        k_gru_mfma<<<GRU_BLOCKS, 256, 0, stream>>>(mbuf, hbuf, WG16, bih, bhh);
    }

    k_head<<<1, 256, 0, stream>>>(hbuf, batch, fcsw, fcsb, f2cw, f2cb, f3cw, f3cb,
                                  f2dw, f2db, f3dw, f3db, (float*)d_out);
}